// Round 13
// baseline (392.484 us; speedup 1.0000x reference)
//
#include <hip/hip_runtime.h>
#include <hip/hip_bf16.h>

typedef unsigned short u16;
typedef unsigned int   u32;
typedef __attribute__((ext_vector_type(8))) short short8;
typedef __attribute__((ext_vector_type(4))) float f32x4;

#define NN 320
#define NP (NN*NN)
#define DD 128
#define NH 4
#define DHH 32
#define QSCALE 0.17677669529663687f
#define LOG2E  1.4426950408889634f

#define MFMA16(A,B,C) __builtin_amdgcn_mfma_f32_16x16x32_bf16(A,B,C,0,0,0)

__device__ __forceinline__ float b2f(u16 u){
    union { u32 i; float f; } v; v.i = ((u32)u) << 16; return v.f;
}
__device__ __forceinline__ u16 f2b(float f){
    union { float f; u32 i; } v; v.f = f;
    u32 x = v.i;
    u32 r = x + 0x7fffu + ((x >> 16) & 1u);
    return (u16)(r >> 16);
}
__device__ __forceinline__ u32 cvtpk(float lo, float hi){
    u32 r; asm("v_cvt_pk_bf16_f32 %0, %1, %2" : "=v"(r) : "v"(lo), "v"(hi)); return r;
}
__device__ __forceinline__ float fexp2(float x){
    float r; asm("v_exp_f32 %0, %1" : "=v"(r) : "v"(x)); return r;
}
__device__ __forceinline__ float frcp(float x){
    float r; asm("v_rcp_f32 %0, %1" : "=v"(r) : "v"(x)); return r;
}

// ---------------- Weight pre-pack: f32 [e][k] -> bf16, 16-slot swizzled ----------------
__global__ __launch_bounds__(256) void k_pack(
    const float* w0, const float* w1, const float* w2, const float* w3, const float* w4,
    const float* w5, const float* w6, const float* w7, const float* w8, const float* w9,
    u16* __restrict__ Wp)
{
    const int m = blockIdx.x >> 3;
    const int rem = ((blockIdx.x & 7) << 8) + threadIdx.x;   // 0..2047 = e*16 + slot
    const float* src;
    switch(m){
        case 0: src=w0; break; case 1: src=w1; break; case 2: src=w2; break;
        case 3: src=w3; break; case 4: src=w4; break; case 5: src=w5; break;
        case 6: src=w6; break; case 7: src=w7; break; case 8: src=w8; break;
        default: src=w9; break;
    }
    const float4 a = *(const float4*)(src + (size_t)rem*8);
    const float4 b = *(const float4*)(src + (size_t)rem*8 + 4);
    union { uint4 q; u16 us[8]; } ww;
    ww.us[0]=f2b(a.x); ww.us[1]=f2b(a.y); ww.us[2]=f2b(a.z); ww.us[3]=f2b(a.w);
    ww.us[4]=f2b(b.x); ww.us[5]=f2b(b.y); ww.us[6]=f2b(b.z); ww.us[7]=f2b(b.w);
    const int e = rem >> 4, slot = rem & 15;
    const int dst = (e << 4) + (slot ^ (e & 15));
    *(uint4*)(Wp + ((size_t)m*2048 + dst)*8) = ww.q;
}

// ---------------- Fused LN + edge-bias + QKVG GEMM ----------------
// P layout: [h][pos][32]. TRP=1 (pass 1): Q and K stored pos-transposed so col-pass
// attn reads Q/K row-style coalesced. V, G normal. bias: f32, attn-tiled layout.
template<int TRP>
__global__ __launch_bounds__(256) void k_lnqkvg(
    const float* __restrict__ xin, const float* __restrict__ ng, const float* __restrict__ nb,
    const float* __restrict__ wb, const u16* __restrict__ Wp, const float* __restrict__ bg,
    float* __restrict__ biasT,
    u16* __restrict__ Pq, u16* __restrict__ Pk, u16* __restrict__ Pv, u16* __restrict__ Pg)
{
    __shared__ u16 As[128*128];   // 32 KB, 16B-slot swizzle: slot ^= row&7
    __shared__ u16 Ws[128*128];   // 32 KB, one phase's W tile (pre-swizzled layout)
    const int tid = threadIdx.x;
    const int pbase = blockIdx.x * 128;
    const int s  = tid & 15;
    const int d0 = s * 8;

    const float4 g0 = *(const float4*)(ng + d0), g1 = *(const float4*)(ng + d0 + 4);
    const float4 b0 = *(const float4*)(nb + d0), b1 = *(const float4*)(nb + d0 + 4);

    #pragma unroll
    for (int c = 0; c < 8; ++c){
        const int row = (tid >> 4) + c*16;
        const int p = pbase + row;
        const float* xr = xin + (size_t)p*DD + d0;
        const float4 xa = *(const float4*)xr, xb = *(const float4*)(xr + 4);
        const float xs[8] = {xa.x,xa.y,xa.z,xa.w,xb.x,xb.y,xb.z,xb.w};
        float sum = 0.f, sq = 0.f;
        #pragma unroll
        for (int u = 0; u < 8; ++u){ sum += xs[u]; sq += xs[u]*xs[u]; }
        #pragma unroll
        for (int m = 1; m < 16; m <<= 1){
            sum += __shfl_xor(sum, m);
            sq  += __shfl_xor(sq,  m);
        }
        const float mu = sum * (1.f/128.f);
        const float var = fmaxf(sq * (1.f/128.f) - mu*mu, 0.f);
        const float rstd = rsqrtf(var + 1e-5f);
        const float gg[8] = {g0.x,g0.y,g0.z,g0.w,g1.x,g1.y,g1.z,g1.w};
        const float bbv[8]= {b0.x,b0.y,b0.z,b0.w,b1.x,b1.y,b1.z,b1.w};
        float y[8];
        #pragma unroll
        for (int u = 0; u < 8; ++u) y[u] = (xs[u]-mu)*rstd*gg[u] + bbv[u];
        uint4 o;
        o.x = cvtpk(y[0],y[1]); o.y = cvtpk(y[2],y[3]);
        o.z = cvtpk(y[4],y[5]); o.w = cvtpk(y[6],y[7]);
        *(uint4*)&As[row*128 + ((s ^ (row & 7)) << 3)] = o;

        float bh0=0.f, bh1=0.f, bh2=0.f, bh3=0.f;
        {
            const float4 wa = *(const float4*)(wb + 0*DD + d0), wv2 = *(const float4*)(wb + 0*DD + d0 + 4);
            const float wv[8] = {wa.x,wa.y,wa.z,wa.w,wv2.x,wv2.y,wv2.z,wv2.w};
            #pragma unroll
            for (int u = 0; u < 8; ++u) bh0 += xs[u]*wv[u];
        }
        {
            const float4 wa = *(const float4*)(wb + 1*DD + d0), wv2 = *(const float4*)(wb + 1*DD + d0 + 4);
            const float wv[8] = {wa.x,wa.y,wa.z,wa.w,wv2.x,wv2.y,wv2.z,wv2.w};
            #pragma unroll
            for (int u = 0; u < 8; ++u) bh1 += xs[u]*wv[u];
        }
        {
            const float4 wa = *(const float4*)(wb + 2*DD + d0), wv2 = *(const float4*)(wb + 2*DD + d0 + 4);
            const float wv[8] = {wa.x,wa.y,wa.z,wa.w,wv2.x,wv2.y,wv2.z,wv2.w};
            #pragma unroll
            for (int u = 0; u < 8; ++u) bh2 += xs[u]*wv[u];
        }
        {
            const float4 wa = *(const float4*)(wb + 3*DD + d0), wv2 = *(const float4*)(wb + 3*DD + d0 + 4);
            const float wv[8] = {wa.x,wa.y,wa.z,wa.w,wv2.x,wv2.y,wv2.z,wv2.w};
            #pragma unroll
            for (int u = 0; u < 8; ++u) bh3 += xs[u]*wv[u];
        }
        #pragma unroll
        for (int m = 1; m < 16; m <<= 1){
            bh0 += __shfl_xor(bh0, m); bh1 += __shfl_xor(bh1, m);
            bh2 += __shfl_xor(bh2, m); bh3 += __shfl_xor(bh3, m);
        }
        if (s < 4){
            const float bsel = (s == 0) ? bh0 : (s == 1) ? bh1 : (s == 2) ? bh2 : bh3;
            const int pi = p / NN, pj = p - pi*NN;
            const int it = pi >> 4, lb = pi & 15;
            const int ch = (pj >= 160) ? 1 : 0;
            const int jj = pj - ch*160;
            const int jt = jj >> 4, rr = jj & 15;
            const int gb = rr >> 2, qb = rr & 3;
            const size_t idx = (((((size_t)s*20 + it)*2 + ch)*10 + jt)*4 + gb)*64 + lb*4 + qb;
            biasT[idx] = bsel * LOG2E;
        }
    }

    const int w = tid >> 6, l = tid & 63;
    const int li = l & 15, g = l >> 4;
    const int wr = w >> 1, wc = w & 1;

    #pragma unroll
    for (int p = 0; p < 4; ++p){
        if (p > 0) __syncthreads();          // drain Ws(p-1) reads
        #pragma unroll
        for (int c = 0; c < 8; ++c){
            const int flat = tid + c*256;
            const uint4 wv = *(const uint4*)(Wp + ((size_t)p*2048 + flat)*8);
            *(uint4*)&Ws[flat*8] = wv;
        }
        __syncthreads();                     // Ws(p) ready (and As on p==0)

        f32x4 acc[4][4] = {};
        #pragma unroll
        for (int ks = 0; ks < 4; ++ks){
            const int slot = ks*4 + g;
            short8 af[4];
            #pragma unroll
            for (int mt = 0; mt < 4; ++mt){
                const int row = wr*64 + mt*16 + li;
                af[mt] = *(const short8*)&As[row*128 + ((slot ^ (row & 7)) << 3)];
            }
            #pragma unroll
            for (int nt = 0; nt < 4; ++nt){
                const int e = wc*64 + nt*16 + li;
                const short8 wf = *(const short8*)&Ws[((e << 4) + (slot ^ (e & 15))) * 8];
                #pragma unroll
                for (int mt = 0; mt < 4; ++mt)
                    acc[mt][nt] = MFMA16(wf, af[mt], acc[mt][nt]);   // D[e][pos]
            }
        }

        u16* Op = (p == 0) ? Pq : (p == 1) ? Pk : (p == 2) ? Pv : Pg;
        #pragma unroll
        for (int mt = 0; mt < 4; ++mt){
            const int pos = pbase + wr*64 + mt*16 + li;
            int ps = pos;
            if (TRP && p < 2){                      // transpose Q and K only
                const int pi = pos / NN, pj = pos - pi*NN;
                ps = pj*NN + pi;
            }
            #pragma unroll
            for (int nt = 0; nt < 4; ++nt){
                const int eb = wc*64 + nt*16 + g*4;
                float v[4];
                #pragma unroll
                for (int q = 0; q < 4; ++q) v[q] = acc[mt][nt][q];
                if (p == 0){
                    #pragma unroll
                    for (int q = 0; q < 4; ++q) v[q] *= (QSCALE * LOG2E);
                } else if (p == 3){
                    #pragma unroll
                    for (int q = 0; q < 4; ++q) v[q] = frcp(1.f + fexp2(-LOG2E*(v[q] + bg[eb+q])));
                }
                uint2 o;
                o.x = cvtpk(v[0], v[1]);
                o.y = cvtpk(v[2], v[3]);
                if (p < 3){
                    u16* dst = Op + ((size_t)(eb >> 5)*NP + ps)*32 + (eb & 31);
                    *(uint2*)dst = o;
                } else {
                    *(uint2*)(Pg + (size_t)pos*DD + eb) = o;
                }
            }
        }
    }
}

// ---------------- Output projection (gated staging; Ws in LDS; float4 epilogue) --------
__global__ __launch_bounds__(256) void k_oproj(
    const u16* __restrict__ Aatt, const u16* __restrict__ Pg, const u16* __restrict__ Wp,
    float* __restrict__ Outp, const float* __restrict__ bov, const float* __restrict__ xres)
{
    __shared__ u16 As[128*128];
    __shared__ u16 Ws[128*128];
    const int tid = threadIdx.x;
    const int pbase = blockIdx.x * 128;

    #pragma unroll
    for (int c = 0; c < 8; ++c){
        const int flat = tid + c*256;
        const int row = flat >> 4, s = flat & 15;
        const size_t off = (size_t)(pbase+row)*DD + s*8;
        union { uint4 q; u16 us[8]; } ua, ug;
        ua.q = *(const uint4*)(Aatt + off);
        ug.q = *(const uint4*)(Pg + off);
        uint4 o;
        o.x = cvtpk(b2f(ua.us[0])*b2f(ug.us[0]), b2f(ua.us[1])*b2f(ug.us[1]));
        o.y = cvtpk(b2f(ua.us[2])*b2f(ug.us[2]), b2f(ua.us[3])*b2f(ug.us[3]));
        o.z = cvtpk(b2f(ua.us[4])*b2f(ug.us[4]), b2f(ua.us[5])*b2f(ug.us[5]));
        o.w = cvtpk(b2f(ua.us[6])*b2f(ug.us[6]), b2f(ua.us[7])*b2f(ug.us[7]));
        *(uint4*)&As[row*128 + ((s ^ (row & 7)) << 3)] = o;
        const uint4 wv = *(const uint4*)(Wp + ((size_t)4*2048 + flat)*8);
        *(uint4*)&Ws[flat*8] = wv;
    }
    __syncthreads();

    const int w = tid >> 6, l = tid & 63;
    const int li = l & 15, g = l >> 4;
    const int wr = w >> 1, wc = w & 1;
    f32x4 acc[4][4] = {};

    #pragma unroll
    for (int ks = 0; ks < 4; ++ks){
        const int slot = ks*4 + g;
        short8 af[4];
        #pragma unroll
        for (int mt = 0; mt < 4; ++mt){
            const int row = wr*64 + mt*16 + li;
            af[mt] = *(const short8*)&As[row*128 + ((slot ^ (row & 7)) << 3)];
        }
        #pragma unroll
        for (int nt = 0; nt < 4; ++nt){
            const int e = wc*64 + nt*16 + li;
            const short8 wf = *(const short8*)&Ws[((e << 4) + (slot ^ (e & 15))) * 8];
            #pragma unroll
            for (int mt = 0; mt < 4; ++mt)
                acc[mt][nt] = MFMA16(wf, af[mt], acc[mt][nt]);   // D[d][pos]
        }
    }

    #pragma unroll
    for (int mt = 0; mt < 4; ++mt){
        const int pos = pbase + wr*64 + mt*16 + li;
        #pragma unroll
        for (int nt = 0; nt < 4; ++nt){
            const int d0 = wc*64 + nt*16 + g*4;
            const float4 xr = *(const float4*)(xres + (size_t)pos*DD + d0);
            const float4 bo4 = *(const float4*)(bov + d0);
            float4 o;
            o.x = acc[mt][nt][0] + bo4.x + xr.x;
            o.y = acc[mt][nt][1] + bo4.y + xr.y;
            o.z = acc[mt][nt][2] + bo4.z + xr.z;
            o.w = acc[mt][nt][3] + bo4.w + xr.w;
            *(float4*)(Outp + (size_t)pos*DD + d0) = o;
        }
    }
}

// ---------------- MFMA attention: K fragments direct from global (no K-LDS) -----------
// Q/K reads always row-style (pass-1 Q,K stored transposed). Only V is LDS-staged
// (20.5 KB LDS -> ~2x blocks/CU). bias f32 tiled, direct f32x4 -> MFMA C-operand.
template<int ROWPASS>
__global__ __launch_bounds__(256) void k_attn_mfma(
    const u16* __restrict__ Pq, const u16* __restrict__ Pk, const u16* __restrict__ Pv,
    const float* __restrict__ biasT, u16* __restrict__ Aout)
{
    __shared__ u16 vt[32*320];   // [e][j'], j' = PV-permuted j, slot swizzle: slot ^= e&7
    const int h = blockIdx.x, r = blockIdx.y;
    const int tid = threadIdx.x;

    const u16* Kh = Pk + (size_t)h*NP*32;
    const u16* Vh = Pv + (size_t)h*NP*32;
    const u16* Qh = Pq + (size_t)h*NP*32;
    const u16* Krow = Kh + (size_t)r*NN*32;   // K slice base, row-style always

    #pragma unroll
    for (int c = 0; c < 5; ++c){
        const int flat = tid + c*256;
        const int j = flat >> 2, s = flat & 3;
        const size_t pos = ROWPASS ? ((size_t)r*NN + j) : ((size_t)j*NN + r);
        const uint4 v4 = *(const uint4*)(Vh + pos*32 + s*8);
        union { uint4 q; u16 us[8]; } vu; vu.q = v4;
        const int jp = (j & ~31) + ((j >> 2) & 3)*8 + ((j >> 4) & 1)*4 + (j & 3);
        #pragma unroll
        for (int u = 0; u < 8; ++u){
            const int e = s*8 + u;
            vt[e*320 + (((jp >> 3) ^ (e & 7)) << 3) + (jp & 7)] = vu.us[u];
        }
    }
    __syncthreads();

    const int w = tid >> 6, l = tid & 63;
    const int li = l & 15, g = l >> 4;

    for (int t = 0; t < 5; ++t){
        const int it = w + t*4;
        const int i0 = it * 16;
        const int iq = i0 + li;
        const size_t qpos_out = ROWPASS ? ((size_t)r*NN + iq) : ((size_t)iq*NN + r);
        const short8 qf = *(const short8*)(Qh + ((size_t)r*NN + iq)*32 + g*8);  // row-style

        float mrun = -3.0e38f;
        float rsum = 0.f;
        f32x4 o0 = {0.f,0.f,0.f,0.f}, o1 = {0.f,0.f,0.f,0.f};

        #pragma unroll
        for (int ch = 0; ch < 2; ++ch){
            // bias -> C operands, coalesced 1KB/wave per jt
            f32x4 st[10];
            const float* bp = biasT + ((((size_t)h*20 + it)*2 + ch)*10)*256 + g*64 + li*4;
            #pragma unroll
            for (int jt = 0; jt < 10; ++jt)
                st[jt] = *(const f32x4*)(bp + jt*256);

            // QK^T: K fragments straight from global (coalesced 1KB/wave per jt, L2-hot)
            #pragma unroll
            for (int jt = 0; jt < 10; ++jt){
                const int jr = ch*160 + jt*16 + li;
                const short8 kf = *(const short8*)(Krow + (size_t)jr*32 + g*8);
                st[jt] = MFMA16(kf, qf, st[jt]);     // S[j][i=li]
            }

            float mx = -3.0e38f;
            #pragma unroll
            for (int jt = 0; jt < 10; ++jt)
                mx = fmaxf(mx, fmaxf(fmaxf(st[jt][0], st[jt][1]), fmaxf(st[jt][2], st[jt][3])));
            mx = fmaxf(mx, __shfl_xor(mx, 16));
            mx = fmaxf(mx, __shfl_xor(mx, 32));
            const float mnew = fmaxf(mrun, mx);
            const float sc = fexp2(mrun - mnew);
            #pragma unroll
            for (int q = 0; q < 4; ++q){ o0[q] *= sc; o1[q] *= sc; }
            rsum *= sc;
            mrun = mnew;

            #pragma unroll
            for (int jt = 0; jt < 10; ++jt){
                #pragma unroll
                for (int q = 0; q < 4; ++q){
                    const float e = fexp2(st[jt][q] - mrun);
                    st[jt][q] = e; rsum += e;
                }
            }

            #pragma unroll
            for (int kt = 0; kt < 5; ++kt){
                union { u32 u[4]; short8 s8; } pu;
                pu.u[0] = cvtpk(st[2*kt][0],   st[2*kt][1]);
                pu.u[1] = cvtpk(st[2*kt][2],   st[2*kt][3]);
                pu.u[2] = cvtpk(st[2*kt+1][0], st[2*kt+1][1]);
                pu.u[3] = cvtpk(st[2*kt+1][2], st[2*kt+1][3]);
                const int ktg = ch*5 + kt;
                const int slot = ((ktg*4 + g) ^ (li & 7)) << 3;
                const short8 v0 = *(const short8*)&vt[li*320 + slot];
                const short8 v1 = *(const short8*)&vt[(16+li)*320 + slot];
                o0 = MFMA16(v0, pu.s8, o0);
                o1 = MFMA16(v1, pu.s8, o1);
            }
        }

        rsum += __shfl_xor(rsum, 16);
        rsum += __shfl_xor(rsum, 32);
        const float inv = frcp(rsum);

        u16* dst = Aout + qpos_out*DD + h*DHH;
        #pragma unroll
        for (int et = 0; et < 2; ++et){
            const f32x4 oo = et ? o1 : o0;
            uint2 o;
            o.x = cvtpk(oo[0]*inv, oo[1]*inv);
            o.y = cvtpk(oo[2]*inv, oo[3]*inv);
            *(uint2*)(dst + et*16 + g*4) = o;
        }
    }
}

// ---------------- host-side launch ----------------
extern "C" void kernel_launch(void* const* d_in, const int* in_sizes, int n_in,
                              void* d_out, int out_size, void* d_ws, size_t ws_size,
                              hipStream_t stream)
{
    const float* x = (const float*)d_in[0];
    float* out = (float*)d_out;
    char* ws = (char*)d_ws;

    u16*   Aatt  = (u16*)ws;                                  // [pos][128] bf16
    float* biasT = (float*)(ws + (size_t)NP*DD*2);            // NH*NP f32, attn-tiled
    u16*   Pq    = (u16*)(ws + (size_t)NP*DD*2 + (size_t)NH*NP*4);  // [h][pos][32]
    u16*   Pk    = Pq + (size_t)NP*DD;
    u16*   Pv    = Pk + (size_t)NP*DD;
    u16*   Pg    = Pv + (size_t)NP*DD;                        // [pos][128]
    u16*   Wpck  = Pg + (size_t)NP*DD;                        // 10*2048*8 bf16 (swizzled)

    {
        const float* w0 = (const float*)d_in[4];               // o_wq
        const float* w1 = (const float*)d_in[5];               // o_wkv (K rows)
        const float* w2 = (const float*)d_in[5] + DD*DD;       // o_wkv (V rows)
        const float* w3 = (const float*)d_in[6];               // o_wg
        const float* w4 = (const float*)d_in[8];               // o_wo
        const float* w5 = (const float*)d_in[13];              // i_wq
        const float* w6 = (const float*)d_in[14];              // i_wkv (K rows)
        const float* w7 = (const float*)d_in[14] + DD*DD;      // i_wkv (V rows)
        const float* w8 = (const float*)d_in[15];              // i_wg
        const float* w9 = (const float*)d_in[17];              // i_wo
        k_pack<<<80, 256, 0, stream>>>(w0,w1,w2,w3,w4,w5,w6,w7,w8,w9, Wpck);
    }

    for (int pass = 0; pass < 2; ++pass){
        void* const* W = d_in + 1 + pass*9;
        const float* ng = (const float*)W[0];
        const float* nb = (const float*)W[1];
        const float* wb = (const float*)W[2];
        const float* bg = (const float*)W[6];
        const float* bo = (const float*)W[8];
        const float* xin = (pass == 0) ? x : out;
        const u16* Wp = Wpck + (size_t)pass*5*2048*8;

        if (pass == 0){
            k_lnqkvg<0><<<NP/128, 256, 0, stream>>>(xin, ng, nb, wb, Wp, bg, biasT, Pq, Pk, Pv, Pg);
            k_attn_mfma<1><<<dim3(NH, NN), 256, 0, stream>>>(Pq, Pk, Pv, biasT, Aatt);
        } else {
            k_lnqkvg<1><<<NP/128, 256, 0, stream>>>(xin, ng, nb, wb, Wp, bg, biasT, Pq, Pk, Pv, Pg);
            k_attn_mfma<0><<<dim3(NH, NN), 256, 0, stream>>>(Pq, Pk, Pv, biasT, Aatt);
        }
        k_oproj<<<NP/128, 256, 0, stream>>>(Aatt, Pg, Wp, out, bo, xin);
    }
}

// Round 14
// 283.259 us; speedup vs baseline: 1.3856x; 1.3856x over previous
//
#include <hip/hip_runtime.h>
#include <hip/hip_bf16.h>

typedef unsigned short u16;
typedef unsigned int   u32;
typedef __attribute__((ext_vector_type(8))) short short8;
typedef __attribute__((ext_vector_type(4))) float f32x4;

#define NN 320
#define NP (NN*NN)
#define DD 128
#define NH 4
#define DHH 32
#define QSCALE 0.17677669529663687f
#define LOG2E  1.4426950408889634f

#define MFMA16(A,B,C) __builtin_amdgcn_mfma_f32_16x16x32_bf16(A,B,C,0,0,0)

__device__ __forceinline__ float b2f(u16 u){
    union { u32 i; float f; } v; v.i = ((u32)u) << 16; return v.f;
}
__device__ __forceinline__ u16 f2b(float f){
    union { float f; u32 i; } v; v.f = f;
    u32 x = v.i;
    u32 r = x + 0x7fffu + ((x >> 16) & 1u);
    return (u16)(r >> 16);
}
__device__ __forceinline__ u32 cvtpk(float lo, float hi){
    u32 r; asm("v_cvt_pk_bf16_f32 %0, %1, %2" : "=v"(r) : "v"(lo), "v"(hi)); return r;
}
__device__ __forceinline__ float fexp2(float x){
    float r; asm("v_exp_f32 %0, %1" : "=v"(r) : "v"(x)); return r;
}
__device__ __forceinline__ float frcp(float x){
    float r; asm("v_rcp_f32 %0, %1" : "=v"(r) : "v"(x)); return r;
}

// ---------------- Weight pre-pack: f32 [e][k] -> bf16, 16-slot swizzled ----------------
__global__ __launch_bounds__(256) void k_pack(
    const float* w0, const float* w1, const float* w2, const float* w3, const float* w4,
    const float* w5, const float* w6, const float* w7, const float* w8, const float* w9,
    u16* __restrict__ Wp)
{
    const int m = blockIdx.x >> 3;
    const int rem = ((blockIdx.x & 7) << 8) + threadIdx.x;   // 0..2047 = e*16 + slot
    const float* src;
    switch(m){
        case 0: src=w0; break; case 1: src=w1; break; case 2: src=w2; break;
        case 3: src=w3; break; case 4: src=w4; break; case 5: src=w5; break;
        case 6: src=w6; break; case 7: src=w7; break; case 8: src=w8; break;
        default: src=w9; break;
    }
    const float4 a = *(const float4*)(src + (size_t)rem*8);
    const float4 b = *(const float4*)(src + (size_t)rem*8 + 4);
    union { uint4 q; u16 us[8]; } ww;
    ww.us[0]=f2b(a.x); ww.us[1]=f2b(a.y); ww.us[2]=f2b(a.z); ww.us[3]=f2b(a.w);
    ww.us[4]=f2b(b.x); ww.us[5]=f2b(b.y); ww.us[6]=f2b(b.z); ww.us[7]=f2b(b.w);
    const int e = rem >> 4, slot = rem & 15;
    const int dst = (e << 4) + (slot ^ (e & 15));
    *(uint4*)(Wp + ((size_t)m*2048 + dst)*8) = ww.q;
}

// ---------------- Fused LN + edge-bias + QKVG GEMM (r9 structure + TRQ + Ws0 prestage) --
// P layout: [h][pos][32]. TRQ=1 (pass 1): Q stored pos-transposed so col-pass attn
// reads Q row-style. bias: f32, attn-tiled layout. Phase-0 W tile staged BEFORE the
// LN prologue so its L2 latency hides under prologue compute.
template<int TRQ>
__global__ __launch_bounds__(256) void k_lnqkvg(
    const float* __restrict__ xin, const float* __restrict__ ng, const float* __restrict__ nb,
    const float* __restrict__ wb, const u16* __restrict__ Wp, const float* __restrict__ bg,
    float* __restrict__ biasT,
    u16* __restrict__ Pq, u16* __restrict__ Pk, u16* __restrict__ Pv, u16* __restrict__ Pg)
{
    __shared__ u16 As[128*128];   // 32 KB, 16B-slot swizzle: slot ^= row&7
    __shared__ u16 Ws[128*128];   // 32 KB, one phase's W tile (pre-swizzled layout)
    const int tid = threadIdx.x;
    const int pbase = blockIdx.x * 128;
    const int s  = tid & 15;
    const int d0 = s * 8;

    // prestage Ws(0): loads issue before the prologue; consumed after the first sync
    #pragma unroll
    for (int c = 0; c < 8; ++c){
        const int flat = tid + c*256;
        const uint4 wv = *(const uint4*)(Wp + (size_t)flat*8);
        *(uint4*)&Ws[flat*8] = wv;
    }

    const float4 g0 = *(const float4*)(ng + d0), g1 = *(const float4*)(ng + d0 + 4);
    const float4 b0 = *(const float4*)(nb + d0), b1 = *(const float4*)(nb + d0 + 4);

    #pragma unroll
    for (int c = 0; c < 8; ++c){
        const int row = (tid >> 4) + c*16;
        const int p = pbase + row;
        const float* xr = xin + (size_t)p*DD + d0;
        const float4 xa = *(const float4*)xr, xb = *(const float4*)(xr + 4);
        const float xs[8] = {xa.x,xa.y,xa.z,xa.w,xb.x,xb.y,xb.z,xb.w};
        float sum = 0.f, sq = 0.f;
        #pragma unroll
        for (int u = 0; u < 8; ++u){ sum += xs[u]; sq += xs[u]*xs[u]; }
        #pragma unroll
        for (int m = 1; m < 16; m <<= 1){
            sum += __shfl_xor(sum, m);
            sq  += __shfl_xor(sq,  m);
        }
        const float mu = sum * (1.f/128.f);
        const float var = fmaxf(sq * (1.f/128.f) - mu*mu, 0.f);
        const float rstd = rsqrtf(var + 1e-5f);
        const float gg[8] = {g0.x,g0.y,g0.z,g0.w,g1.x,g1.y,g1.z,g1.w};
        const float bbv[8]= {b0.x,b0.y,b0.z,b0.w,b1.x,b1.y,b1.z,b1.w};
        float y[8];
        #pragma unroll
        for (int u = 0; u < 8; ++u) y[u] = (xs[u]-mu)*rstd*gg[u] + bbv[u];
        uint4 o;
        o.x = cvtpk(y[0],y[1]); o.y = cvtpk(y[2],y[3]);
        o.z = cvtpk(y[4],y[5]); o.w = cvtpk(y[6],y[7]);
        *(uint4*)&As[row*128 + ((s ^ (row & 7)) << 3)] = o;

        float bh0=0.f, bh1=0.f, bh2=0.f, bh3=0.f;
        {
            const float4 wa = *(const float4*)(wb + 0*DD + d0), wv2 = *(const float4*)(wb + 0*DD + d0 + 4);
            const float wv[8] = {wa.x,wa.y,wa.z,wa.w,wv2.x,wv2.y,wv2.z,wv2.w};
            #pragma unroll
            for (int u = 0; u < 8; ++u) bh0 += xs[u]*wv[u];
        }
        {
            const float4 wa = *(const float4*)(wb + 1*DD + d0), wv2 = *(const float4*)(wb + 1*DD + d0 + 4);
            const float wv[8] = {wa.x,wa.y,wa.z,wa.w,wv2.x,wv2.y,wv2.z,wv2.w};
            #pragma unroll
            for (int u = 0; u < 8; ++u) bh1 += xs[u]*wv[u];
        }
        {
            const float4 wa = *(const float4*)(wb + 2*DD + d0), wv2 = *(const float4*)(wb + 2*DD + d0 + 4);
            const float wv[8] = {wa.x,wa.y,wa.z,wa.w,wv2.x,wv2.y,wv2.z,wv2.w};
            #pragma unroll
            for (int u = 0; u < 8; ++u) bh2 += xs[u]*wv[u];
        }
        {
            const float4 wa = *(const float4*)(wb + 3*DD + d0), wv2 = *(const float4*)(wb + 3*DD + d0 + 4);
            const float wv[8] = {wa.x,wa.y,wa.z,wa.w,wv2.x,wv2.y,wv2.z,wv2.w};
            #pragma unroll
            for (int u = 0; u < 8; ++u) bh3 += xs[u]*wv[u];
        }
        #pragma unroll
        for (int m = 1; m < 16; m <<= 1){
            bh0 += __shfl_xor(bh0, m); bh1 += __shfl_xor(bh1, m);
            bh2 += __shfl_xor(bh2, m); bh3 += __shfl_xor(bh3, m);
        }
        if (s < 4){
            const float bsel = (s == 0) ? bh0 : (s == 1) ? bh1 : (s == 2) ? bh2 : bh3;
            const int pi = p / NN, pj = p - pi*NN;
            const int it = pi >> 4, lb = pi & 15;
            const int ch = (pj >= 160) ? 1 : 0;
            const int jj = pj - ch*160;
            const int jt = jj >> 4, rr = jj & 15;
            const int gb = rr >> 2, qb = rr & 3;
            const size_t idx = (((((size_t)s*20 + it)*2 + ch)*10 + jt)*4 + gb)*64 + lb*4 + qb;
            biasT[idx] = bsel * LOG2E;
        }
    }

    const int w = tid >> 6, l = tid & 63;
    const int li = l & 15, g = l >> 4;
    const int wr = w >> 1, wc = w & 1;

    #pragma unroll
    for (int p = 0; p < 4; ++p){
        if (p > 0){
            __syncthreads();                 // drain Ws(p-1) reads
            #pragma unroll
            for (int c = 0; c < 8; ++c){
                const int flat = tid + c*256;
                const uint4 wv = *(const uint4*)(Wp + ((size_t)p*2048 + flat)*8);
                *(uint4*)&Ws[flat*8] = wv;
            }
        }
        __syncthreads();                     // Ws(p) ready (p==0: As+Ws0 ready)

        f32x4 acc[4][4] = {};
        #pragma unroll
        for (int ks = 0; ks < 4; ++ks){
            const int slot = ks*4 + g;
            short8 af[4];
            #pragma unroll
            for (int mt = 0; mt < 4; ++mt){
                const int row = wr*64 + mt*16 + li;
                af[mt] = *(const short8*)&As[row*128 + ((slot ^ (row & 7)) << 3)];
            }
            #pragma unroll
            for (int nt = 0; nt < 4; ++nt){
                const int e = wc*64 + nt*16 + li;
                const short8 wf = *(const short8*)&Ws[((e << 4) + (slot ^ (e & 15))) * 8];
                #pragma unroll
                for (int mt = 0; mt < 4; ++mt)
                    acc[mt][nt] = MFMA16(wf, af[mt], acc[mt][nt]);   // D[e][pos]
            }
        }

        u16* Op = (p == 0) ? Pq : (p == 1) ? Pk : (p == 2) ? Pv : Pg;
        #pragma unroll
        for (int mt = 0; mt < 4; ++mt){
            const int pos = pbase + wr*64 + mt*16 + li;
            int ps = pos;
            if (TRQ && p == 0){                      // transpose Q only
                const int pi = pos / NN, pj = pos - pi*NN;
                ps = pj*NN + pi;
            }
            #pragma unroll
            for (int nt = 0; nt < 4; ++nt){
                const int eb = wc*64 + nt*16 + g*4;
                float v[4];
                #pragma unroll
                for (int q = 0; q < 4; ++q) v[q] = acc[mt][nt][q];
                if (p == 0){
                    #pragma unroll
                    for (int q = 0; q < 4; ++q) v[q] *= (QSCALE * LOG2E);
                } else if (p == 3){
                    #pragma unroll
                    for (int q = 0; q < 4; ++q) v[q] = frcp(1.f + fexp2(-LOG2E*(v[q] + bg[eb+q])));
                }
                uint2 o;
                o.x = cvtpk(v[0], v[1]);
                o.y = cvtpk(v[2], v[3]);
                if (p < 3){
                    u16* dst = Op + ((size_t)(eb >> 5)*NP + ps)*32 + (eb & 31);
                    *(uint2*)dst = o;
                } else {
                    *(uint2*)(Pg + (size_t)pos*DD + eb) = o;
                }
            }
        }
    }
}

// ---------------- Output projection (gated staging; Ws in LDS; float4 epilogue) --------
__global__ __launch_bounds__(256) void k_oproj(
    const u16* __restrict__ Aatt, const u16* __restrict__ Pg, const u16* __restrict__ Wp,
    float* __restrict__ Outp, const float* __restrict__ bov, const float* __restrict__ xres)
{
    __shared__ u16 As[128*128];
    __shared__ u16 Ws[128*128];
    const int tid = threadIdx.x;
    const int pbase = blockIdx.x * 128;

    #pragma unroll
    for (int c = 0; c < 8; ++c){
        const int flat = tid + c*256;
        const int row = flat >> 4, s = flat & 15;
        const size_t off = (size_t)(pbase+row)*DD + s*8;
        union { uint4 q; u16 us[8]; } ua, ug;
        ua.q = *(const uint4*)(Aatt + off);
        ug.q = *(const uint4*)(Pg + off);
        uint4 o;
        o.x = cvtpk(b2f(ua.us[0])*b2f(ug.us[0]), b2f(ua.us[1])*b2f(ug.us[1]));
        o.y = cvtpk(b2f(ua.us[2])*b2f(ug.us[2]), b2f(ua.us[3])*b2f(ug.us[3]));
        o.z = cvtpk(b2f(ua.us[4])*b2f(ug.us[4]), b2f(ua.us[5])*b2f(ug.us[5]));
        o.w = cvtpk(b2f(ua.us[6])*b2f(ug.us[6]), b2f(ua.us[7])*b2f(ug.us[7]));
        *(uint4*)&As[row*128 + ((s ^ (row & 7)) << 3)] = o;
        const uint4 wv = *(const uint4*)(Wp + ((size_t)4*2048 + flat)*8);
        *(uint4*)&Ws[flat*8] = wv;
    }
    __syncthreads();

    const int w = tid >> 6, l = tid & 63;
    const int li = l & 15, g = l >> 4;
    const int wr = w >> 1, wc = w & 1;
    f32x4 acc[4][4] = {};

    #pragma unroll
    for (int ks = 0; ks < 4; ++ks){
        const int slot = ks*4 + g;
        short8 af[4];
        #pragma unroll
        for (int mt = 0; mt < 4; ++mt){
            const int row = wr*64 + mt*16 + li;
            af[mt] = *(const short8*)&As[row*128 + ((slot ^ (row & 7)) << 3)];
        }
        #pragma unroll
        for (int nt = 0; nt < 4; ++nt){
            const int e = wc*64 + nt*16 + li;
            const short8 wf = *(const short8*)&Ws[((e << 4) + (slot ^ (e & 15))) * 8];
            #pragma unroll
            for (int mt = 0; mt < 4; ++mt)
                acc[mt][nt] = MFMA16(wf, af[mt], acc[mt][nt]);   // D[d][pos]
        }
    }

    #pragma unroll
    for (int mt = 0; mt < 4; ++mt){
        const int pos = pbase + wr*64 + mt*16 + li;
        #pragma unroll
        for (int nt = 0; nt < 4; ++nt){
            const int d0 = wc*64 + nt*16 + g*4;
            const float4 xr = *(const float4*)(xres + (size_t)pos*DD + d0);
            const float4 bo4 = *(const float4*)(bov + d0);
            float4 o;
            o.x = acc[mt][nt][0] + bo4.x + xr.x;
            o.y = acc[mt][nt][1] + bo4.y + xr.y;
            o.z = acc[mt][nt][2] + bo4.z + xr.z;
            o.w = acc[mt][nt][3] + bo4.w + xr.w;
            *(float4*)(Outp + (size_t)pos*DD + d0) = o;
        }
    }
}

// ---------------- MFMA attention (r9 structure; Q always row-style via TRQ) -----------
template<int ROWPASS>
__global__ __launch_bounds__(256) void k_attn_mfma(
    const u16* __restrict__ Pq, const u16* __restrict__ Pk, const u16* __restrict__ Pv,
    const float* __restrict__ biasT, u16* __restrict__ Aout)
{
    __shared__ u16 ksm[320*32];  // [j][e], 16B-slot swizzle: slot ^= (j>>1)&3
    __shared__ u16 vt[32*320];   // [e][j'], j' = PV-permuted j, slot swizzle: slot ^= e&7
    const int h = blockIdx.x, r = blockIdx.y;
    const int tid = threadIdx.x;

    const u16* Kh = Pk + (size_t)h*NP*32;
    const u16* Vh = Pv + (size_t)h*NP*32;
    const u16* Qh = Pq + (size_t)h*NP*32;

    #pragma unroll
    for (int c = 0; c < 5; ++c){
        const int flat = tid + c*256;
        const int j = flat >> 2, s = flat & 3;
        const size_t pos = ROWPASS ? ((size_t)r*NN + j) : ((size_t)j*NN + r);
        const uint4 k4 = *(const uint4*)(Kh + pos*32 + s*8);
        *(uint4*)&ksm[j*32 + ((s ^ ((j >> 1) & 3)) << 3)] = k4;
        const uint4 v4 = *(const uint4*)(Vh + pos*32 + s*8);
        union { uint4 q; u16 us[8]; } vu; vu.q = v4;
        const int jp = (j & ~31) + ((j >> 2) & 3)*8 + ((j >> 4) & 1)*4 + (j & 3);
        #pragma unroll
        for (int u = 0; u < 8; ++u){
            const int e = s*8 + u;
            vt[e*320 + (((jp >> 3) ^ (e & 7)) << 3) + (jp & 7)] = vu.us[u];
        }
    }
    __syncthreads();

    const int w = tid >> 6, l = tid & 63;
    const int li = l & 15, g = l >> 4;

    for (int t = 0; t < 5; ++t){
        const int it = w + t*4;
        const int i0 = it * 16;
        const int iq = i0 + li;
        const size_t qpos_out = ROWPASS ? ((size_t)r*NN + iq) : ((size_t)iq*NN + r);
        const short8 qf = *(const short8*)(Qh + ((size_t)r*NN + iq)*32 + g*8);  // row-style (TRQ)

        float mrun = -3.0e38f;
        float rsum = 0.f;
        f32x4 o0 = {0.f,0.f,0.f,0.f}, o1 = {0.f,0.f,0.f,0.f};

        #pragma unroll
        for (int ch = 0; ch < 2; ++ch){
            f32x4 st[10];
            const float* bp = biasT + ((((size_t)h*20 + it)*2 + ch)*10)*256 + g*64 + li*4;
            #pragma unroll
            for (int jt = 0; jt < 10; ++jt)
                st[jt] = *(const f32x4*)(bp + jt*256);

            #pragma unroll
            for (int jt = 0; jt < 10; ++jt){
                const int jr = ch*160 + jt*16 + li;
                const short8 kf = *(const short8*)&ksm[jr*32 + ((g ^ ((jr >> 1) & 3)) << 3)];
                st[jt] = MFMA16(kf, qf, st[jt]);     // S[j][i=li]
            }

            float mx = -3.0e38f;
            #pragma unroll
            for (int jt = 0; jt < 10; ++jt)
                mx = fmaxf(mx, fmaxf(fmaxf(st[jt][0], st[jt][1]), fmaxf(st[jt][2], st[jt][3])));
            mx = fmaxf(mx, __shfl_xor(mx, 16));
            mx = fmaxf(mx, __shfl_xor(mx, 32));
            const float mnew = fmaxf(mrun, mx);
            const float sc = fexp2(mrun - mnew);
            #pragma unroll
            for (int q = 0; q < 4; ++q){ o0[q] *= sc; o1[q] *= sc; }
            rsum *= sc;
            mrun = mnew;

            #pragma unroll
            for (int jt = 0; jt < 10; ++jt){
                #pragma unroll
                for (int q = 0; q < 4; ++q){
                    const float e = fexp2(st[jt][q] - mrun);
                    st[jt][q] = e; rsum += e;
                }
            }

            #pragma unroll
            for (int kt = 0; kt < 5; ++kt){
                union { u32 u[4]; short8 s8; } pu;
                pu.u[0] = cvtpk(st[2*kt][0],   st[2*kt][1]);
                pu.u[1] = cvtpk(st[2*kt][2],   st[2*kt][3]);
                pu.u[2] = cvtpk(st[2*kt+1][0], st[2*kt+1][1]);
                pu.u[3] = cvtpk(st[2*kt+1][2], st[2*kt+1][3]);
                const int ktg = ch*5 + kt;
                const int slot = ((ktg*4 + g) ^ (li & 7)) << 3;
                const short8 v0 = *(const short8*)&vt[li*320 + slot];
                const short8 v1 = *(const short8*)&vt[(16+li)*320 + slot];
                o0 = MFMA16(v0, pu.s8, o0);
                o1 = MFMA16(v1, pu.s8, o1);
            }
        }

        rsum += __shfl_xor(rsum, 16);
        rsum += __shfl_xor(rsum, 32);
        const float inv = frcp(rsum);

        u16* dst = Aout + qpos_out*DD + h*DHH;
        #pragma unroll
        for (int et = 0; et < 2; ++et){
            const f32x4 oo = et ? o1 : o0;
            uint2 o;
            o.x = cvtpk(oo[0]*inv, oo[1]*inv);
            o.y = cvtpk(oo[2]*inv, oo[3]*inv);
            *(uint2*)(dst + et*16 + g*4) = o;
        }
    }
}

// ---------------- host-side launch ----------------
extern "C" void kernel_launch(void* const* d_in, const int* in_sizes, int n_in,
                              void* d_out, int out_size, void* d_ws, size_t ws_size,
                              hipStream_t stream)
{
    const float* x = (const float*)d_in[0];
    float* out = (float*)d_out;
    char* ws = (char*)d_ws;

    u16*   Aatt  = (u16*)ws;                                  // [pos][128] bf16
    float* biasT = (float*)(ws + (size_t)NP*DD*2);            // NH*NP f32, attn-tiled
    u16*   Pq    = (u16*)(ws + (size_t)NP*DD*2 + (size_t)NH*NP*4);  // [h][pos][32]
    u16*   Pk    = Pq + (size_t)NP*DD;
    u16*   Pv    = Pk + (size_t)NP*DD;
    u16*   Pg    = Pv + (size_t)NP*DD;                        // [pos][128]
    u16*   Wpck  = Pg + (size_t)NP*DD;                        // 10*2048*8 bf16 (swizzled)

    {
        const float* w0 = (const float*)d_in[4];               // o_wq
        const float* w1 = (const float*)d_in[5];               // o_wkv (K rows)
        const float* w2 = (const float*)d_in[5] + DD*DD;       // o_wkv (V rows)
        const float* w3 = (const float*)d_in[6];               // o_wg
        const float* w4 = (const float*)d_in[8];               // o_wo
        const float* w5 = (const float*)d_in[13];              // i_wq
        const float* w6 = (const float*)d_in[14];              // i_wkv (K rows)
        const float* w7 = (const float*)d_in[14] + DD*DD;      // i_wkv (V rows)
        const float* w8 = (const float*)d_in[15];              // i_wg
        const float* w9 = (const float*)d_in[17];              // i_wo
        k_pack<<<80, 256, 0, stream>>>(w0,w1,w2,w3,w4,w5,w6,w7,w8,w9, Wpck);
    }

    for (int pass = 0; pass < 2; ++pass){
        void* const* W = d_in + 1 + pass*9;
        const float* ng = (const float*)W[0];
        const float* nb = (const float*)W[1];
        const float* wb = (const float*)W[2];
        const float* bg = (const float*)W[6];
        const float* bo = (const float*)W[8];
        const float* xin = (pass == 0) ? x : out;
        const u16* Wp = Wpck + (size_t)pass*5*2048*8;

        if (pass == 0){
            k_lnqkvg<0><<<NP/128, 256, 0, stream>>>(xin, ng, nb, wb, Wp, bg, biasT, Pq, Pk, Pv, Pg);
            k_attn_mfma<1><<<dim3(NH, NN), 256, 0, stream>>>(Pq, Pk, Pv, biasT, Aatt);
        } else {
            k_lnqkvg<1><<<NP/128, 256, 0, stream>>>(xin, ng, nb, wb, Wp, bg, biasT, Pq, Pk, Pv, Pg);
            k_attn_mfma<0><<<dim3(NH, NN), 256, 0, stream>>>(Pq, Pk, Pv, biasT, Aatt);
        }
        k_oproj<<<NP/128, 256, 0, stream>>>(Aatt, Pg, Wp, out, bo, xin);
    }
}

// Round 15
// 268.743 us; speedup vs baseline: 1.4604x; 1.0540x over previous
//
#include <hip/hip_runtime.h>
#include <hip/hip_bf16.h>

typedef unsigned short u16;
typedef unsigned int   u32;
typedef __attribute__((ext_vector_type(8))) short short8;
typedef __attribute__((ext_vector_type(4))) float f32x4;

#define NN 320
#define NP (NN*NN)
#define DD 128
#define NH 4
#define DHH 32
#define QSCALE 0.17677669529663687f
#define LOG2E  1.4426950408889634f

#define MFMA16(A,B,C) __builtin_amdgcn_mfma_f32_16x16x32_bf16(A,B,C,0,0,0)

__device__ __forceinline__ float b2f(u16 u){
    union { u32 i; float f; } v; v.i = ((u32)u) << 16; return v.f;
}
__device__ __forceinline__ u16 f2b(float f){
    union { float f; u32 i; } v; v.f = f;
    u32 x = v.i;
    u32 r = x + 0x7fffu + ((x >> 16) & 1u);
    return (u16)(r >> 16);
}
__device__ __forceinline__ u32 cvtpk(float lo, float hi){
    u32 r; asm("v_cvt_pk_bf16_f32 %0, %1, %2" : "=v"(r) : "v"(lo), "v"(hi)); return r;
}
__device__ __forceinline__ float fexp2(float x){
    float r; asm("v_exp_f32 %0, %1" : "=v"(r) : "v"(x)); return r;
}
__device__ __forceinline__ float frcp(float x){
    float r; asm("v_rcp_f32 %0, %1" : "=v"(r) : "v"(x)); return r;
}
// async global->LDS, 16B per lane; LDS dest must be wave-uniform base + lane*16
__device__ __forceinline__ void gld_lds16(const u16* gp, u16* lp){
    __builtin_amdgcn_global_load_lds(
        (const __attribute__((address_space(1))) unsigned int*)gp,
        (__attribute__((address_space(3))) unsigned int*)lp, 16, 0, 0);
}

// ---------------- Weight pre-pack: f32 [e][k] -> bf16, 16-slot swizzled ----------------
__global__ __launch_bounds__(256) void k_pack(
    const float* w0, const float* w1, const float* w2, const float* w3, const float* w4,
    const float* w5, const float* w6, const float* w7, const float* w8, const float* w9,
    u16* __restrict__ Wp)
{
    const int m = blockIdx.x >> 3;
    const int rem = ((blockIdx.x & 7) << 8) + threadIdx.x;   // 0..2047 = e*16 + slot
    const float* src;
    switch(m){
        case 0: src=w0; break; case 1: src=w1; break; case 2: src=w2; break;
        case 3: src=w3; break; case 4: src=w4; break; case 5: src=w5; break;
        case 6: src=w6; break; case 7: src=w7; break; case 8: src=w8; break;
        default: src=w9; break;
    }
    const float4 a = *(const float4*)(src + (size_t)rem*8);
    const float4 b = *(const float4*)(src + (size_t)rem*8 + 4);
    union { uint4 q; u16 us[8]; } ww;
    ww.us[0]=f2b(a.x); ww.us[1]=f2b(a.y); ww.us[2]=f2b(a.z); ww.us[3]=f2b(a.w);
    ww.us[4]=f2b(b.x); ww.us[5]=f2b(b.y); ww.us[6]=f2b(b.z); ww.us[7]=f2b(b.w);
    const int e = rem >> 4, slot = rem & 15;
    const int dst = (e << 4) + (slot ^ (e & 15));
    *(uint4*)(Wp + ((size_t)m*2048 + dst)*8) = ww.q;
}

// ---------------- Fused LN + edge-bias + QKVG GEMM (Ws via global_load_lds) ------------
// P layout: [h][pos][32]. TRQ=1 (pass 1): Q stored pos-transposed so col-pass attn
// reads Q row-style. bias: f32, attn-tiled layout. All Ws stages are async DMA
// (no VGPR round trip); phase-0 DMA issues before the LN prologue and drains at the
// first barrier.
template<int TRQ>
__global__ __launch_bounds__(256) void k_lnqkvg(
    const float* __restrict__ xin, const float* __restrict__ ng, const float* __restrict__ nb,
    const float* __restrict__ wb, const u16* __restrict__ Wp, const float* __restrict__ bg,
    float* __restrict__ biasT,
    u16* __restrict__ Pq, u16* __restrict__ Pk, u16* __restrict__ Pv, u16* __restrict__ Pg)
{
    __shared__ u16 As[128*128];   // 32 KB, 16B-slot swizzle: slot ^= row&7
    __shared__ u16 Ws[128*128];   // 32 KB, one phase's W tile (pre-swizzled layout)
    const int tid = threadIdx.x;
    const int pbase = blockIdx.x * 128;
    const int s  = tid & 15;
    const int d0 = s * 8;

    // prestage Ws(0) via async DMA: issues before the prologue, drains at first barrier
    #pragma unroll
    for (int c = 0; c < 8; ++c){
        const int flat = tid + c*256;
        gld_lds16(Wp + (size_t)flat*8, &Ws[flat*8]);
    }

    const float4 g0 = *(const float4*)(ng + d0), g1 = *(const float4*)(ng + d0 + 4);
    const float4 b0 = *(const float4*)(nb + d0), b1 = *(const float4*)(nb + d0 + 4);

    #pragma unroll
    for (int c = 0; c < 8; ++c){
        const int row = (tid >> 4) + c*16;
        const int p = pbase + row;
        const float* xr = xin + (size_t)p*DD + d0;
        const float4 xa = *(const float4*)xr, xb = *(const float4*)(xr + 4);
        const float xs[8] = {xa.x,xa.y,xa.z,xa.w,xb.x,xb.y,xb.z,xb.w};
        float sum = 0.f, sq = 0.f;
        #pragma unroll
        for (int u = 0; u < 8; ++u){ sum += xs[u]; sq += xs[u]*xs[u]; }
        #pragma unroll
        for (int m = 1; m < 16; m <<= 1){
            sum += __shfl_xor(sum, m);
            sq  += __shfl_xor(sq,  m);
        }
        const float mu = sum * (1.f/128.f);
        const float var = fmaxf(sq * (1.f/128.f) - mu*mu, 0.f);
        const float rstd = rsqrtf(var + 1e-5f);
        const float gg[8] = {g0.x,g0.y,g0.z,g0.w,g1.x,g1.y,g1.z,g1.w};
        const float bbv[8]= {b0.x,b0.y,b0.z,b0.w,b1.x,b1.y,b1.z,b1.w};
        float y[8];
        #pragma unroll
        for (int u = 0; u < 8; ++u) y[u] = (xs[u]-mu)*rstd*gg[u] + bbv[u];
        uint4 o;
        o.x = cvtpk(y[0],y[1]); o.y = cvtpk(y[2],y[3]);
        o.z = cvtpk(y[4],y[5]); o.w = cvtpk(y[6],y[7]);
        *(uint4*)&As[row*128 + ((s ^ (row & 7)) << 3)] = o;

        float bh0=0.f, bh1=0.f, bh2=0.f, bh3=0.f;
        {
            const float4 wa = *(const float4*)(wb + 0*DD + d0), wv2 = *(const float4*)(wb + 0*DD + d0 + 4);
            const float wv[8] = {wa.x,wa.y,wa.z,wa.w,wv2.x,wv2.y,wv2.z,wv2.w};
            #pragma unroll
            for (int u = 0; u < 8; ++u) bh0 += xs[u]*wv[u];
        }
        {
            const float4 wa = *(const float4*)(wb + 1*DD + d0), wv2 = *(const float4*)(wb + 1*DD + d0 + 4);
            const float wv[8] = {wa.x,wa.y,wa.z,wa.w,wv2.x,wv2.y,wv2.z,wv2.w};
            #pragma unroll
            for (int u = 0; u < 8; ++u) bh1 += xs[u]*wv[u];
        }
        {
            const float4 wa = *(const float4*)(wb + 2*DD + d0), wv2 = *(const float4*)(wb + 2*DD + d0 + 4);
            const float wv[8] = {wa.x,wa.y,wa.z,wa.w,wv2.x,wv2.y,wv2.z,wv2.w};
            #pragma unroll
            for (int u = 0; u < 8; ++u) bh2 += xs[u]*wv[u];
        }
        {
            const float4 wa = *(const float4*)(wb + 3*DD + d0), wv2 = *(const float4*)(wb + 3*DD + d0 + 4);
            const float wv[8] = {wa.x,wa.y,wa.z,wa.w,wv2.x,wv2.y,wv2.z,wv2.w};
            #pragma unroll
            for (int u = 0; u < 8; ++u) bh3 += xs[u]*wv[u];
        }
        #pragma unroll
        for (int m = 1; m < 16; m <<= 1){
            bh0 += __shfl_xor(bh0, m); bh1 += __shfl_xor(bh1, m);
            bh2 += __shfl_xor(bh2, m); bh3 += __shfl_xor(bh3, m);
        }
        if (s < 4){
            const float bsel = (s == 0) ? bh0 : (s == 1) ? bh1 : (s == 2) ? bh2 : bh3;
            const int pi = p / NN, pj = p - pi*NN;
            const int it = pi >> 4, lb = pi & 15;
            const int ch = (pj >= 160) ? 1 : 0;
            const int jj = pj - ch*160;
            const int jt = jj >> 4, rr = jj & 15;
            const int gb = rr >> 2, qb = rr & 3;
            const size_t idx = (((((size_t)s*20 + it)*2 + ch)*10 + jt)*4 + gb)*64 + lb*4 + qb;
            biasT[idx] = bsel * LOG2E;
        }
    }

    const int w = tid >> 6, l = tid & 63;
    const int li = l & 15, g = l >> 4;
    const int wr = w >> 1, wc = w & 1;

    #pragma unroll
    for (int p = 0; p < 4; ++p){
        if (p > 0){
            __syncthreads();                 // drain Ws(p-1) reads
            #pragma unroll
            for (int c = 0; c < 8; ++c){
                const int flat = tid + c*256;
                gld_lds16(Wp + ((size_t)p*2048 + flat)*8, &Ws[flat*8]);
            }
        }
        __syncthreads();                     // Ws(p) DMA drained (p==0: As+Ws0 ready)

        f32x4 acc[4][4] = {};
        #pragma unroll
        for (int ks = 0; ks < 4; ++ks){
            const int slot = ks*4 + g;
            short8 af[4];
            #pragma unroll
            for (int mt = 0; mt < 4; ++mt){
                const int row = wr*64 + mt*16 + li;
                af[mt] = *(const short8*)&As[row*128 + ((slot ^ (row & 7)) << 3)];
            }
            #pragma unroll
            for (int nt = 0; nt < 4; ++nt){
                const int e = wc*64 + nt*16 + li;
                const short8 wf = *(const short8*)&Ws[((e << 4) + (slot ^ (e & 15))) * 8];
                #pragma unroll
                for (int mt = 0; mt < 4; ++mt)
                    acc[mt][nt] = MFMA16(wf, af[mt], acc[mt][nt]);   // D[e][pos]
            }
        }

        u16* Op = (p == 0) ? Pq : (p == 1) ? Pk : (p == 2) ? Pv : Pg;
        #pragma unroll
        for (int mt = 0; mt < 4; ++mt){
            const int pos = pbase + wr*64 + mt*16 + li;
            int ps = pos;
            if (TRQ && p == 0){                      // transpose Q only
                const int pi = pos / NN, pj = pos - pi*NN;
                ps = pj*NN + pi;
            }
            #pragma unroll
            for (int nt = 0; nt < 4; ++nt){
                const int eb = wc*64 + nt*16 + g*4;
                float v[4];
                #pragma unroll
                for (int q = 0; q < 4; ++q) v[q] = acc[mt][nt][q];
                if (p == 0){
                    #pragma unroll
                    for (int q = 0; q < 4; ++q) v[q] *= (QSCALE * LOG2E);
                } else if (p == 3){
                    #pragma unroll
                    for (int q = 0; q < 4; ++q) v[q] = frcp(1.f + fexp2(-LOG2E*(v[q] + bg[eb+q])));
                }
                uint2 o;
                o.x = cvtpk(v[0], v[1]);
                o.y = cvtpk(v[2], v[3]);
                if (p < 3){
                    u16* dst = Op + ((size_t)(eb >> 5)*NP + ps)*32 + (eb & 31);
                    *(uint2*)dst = o;
                } else {
                    *(uint2*)(Pg + (size_t)pos*DD + eb) = o;
                }
            }
        }
    }
}

// ---------------- Output projection (gated staging; Ws via global_load_lds) ------------
__global__ __launch_bounds__(256) void k_oproj(
    const u16* __restrict__ Aatt, const u16* __restrict__ Pg, const u16* __restrict__ Wp,
    float* __restrict__ Outp, const float* __restrict__ bov, const float* __restrict__ xres)
{
    __shared__ u16 As[128*128];
    __shared__ u16 Ws[128*128];
    const int tid = threadIdx.x;
    const int pbase = blockIdx.x * 128;

    // async Ws DMA first: streams while the gated A-staging computes
    #pragma unroll
    for (int c = 0; c < 8; ++c){
        const int flat = tid + c*256;
        gld_lds16(Wp + ((size_t)4*2048 + flat)*8, &Ws[flat*8]);
    }

    #pragma unroll
    for (int c = 0; c < 8; ++c){
        const int flat = tid + c*256;
        const int row = flat >> 4, s = flat & 15;
        const size_t off = (size_t)(pbase+row)*DD + s*8;
        union { uint4 q; u16 us[8]; } ua, ug;
        ua.q = *(const uint4*)(Aatt + off);
        ug.q = *(const uint4*)(Pg + off);
        uint4 o;
        o.x = cvtpk(b2f(ua.us[0])*b2f(ug.us[0]), b2f(ua.us[1])*b2f(ug.us[1]));
        o.y = cvtpk(b2f(ua.us[2])*b2f(ug.us[2]), b2f(ua.us[3])*b2f(ug.us[3]));
        o.z = cvtpk(b2f(ua.us[4])*b2f(ug.us[4]), b2f(ua.us[5])*b2f(ug.us[5]));
        o.w = cvtpk(b2f(ua.us[6])*b2f(ug.us[6]), b2f(ua.us[7])*b2f(ug.us[7]));
        *(uint4*)&As[row*128 + ((s ^ (row & 7)) << 3)] = o;
    }
    __syncthreads();

    const int w = tid >> 6, l = tid & 63;
    const int li = l & 15, g = l >> 4;
    const int wr = w >> 1, wc = w & 1;
    f32x4 acc[4][4] = {};

    #pragma unroll
    for (int ks = 0; ks < 4; ++ks){
        const int slot = ks*4 + g;
        short8 af[4];
        #pragma unroll
        for (int mt = 0; mt < 4; ++mt){
            const int row = wr*64 + mt*16 + li;
            af[mt] = *(const short8*)&As[row*128 + ((slot ^ (row & 7)) << 3)];
        }
        #pragma unroll
        for (int nt = 0; nt < 4; ++nt){
            const int e = wc*64 + nt*16 + li;
            const short8 wf = *(const short8*)&Ws[((e << 4) + (slot ^ (e & 15))) * 8];
            #pragma unroll
            for (int mt = 0; mt < 4; ++mt)
                acc[mt][nt] = MFMA16(wf, af[mt], acc[mt][nt]);   // D[d][pos]
        }
    }

    #pragma unroll
    for (int mt = 0; mt < 4; ++mt){
        const int pos = pbase + wr*64 + mt*16 + li;
        #pragma unroll
        for (int nt = 0; nt < 4; ++nt){
            const int d0 = wc*64 + nt*16 + g*4;
            const float4 xr = *(const float4*)(xres + (size_t)pos*DD + d0);
            const float4 bo4 = *(const float4*)(bov + d0);
            float4 o;
            o.x = acc[mt][nt][0] + bo4.x + xr.x;
            o.y = acc[mt][nt][1] + bo4.y + xr.y;
            o.z = acc[mt][nt][2] + bo4.z + xr.z;
            o.w = acc[mt][nt][3] + bo4.w + xr.w;
            *(float4*)(Outp + (size_t)pos*DD + d0) = o;
        }
    }
}

// ---------------- MFMA attention (r9 structure; Q always row-style via TRQ) -----------
template<int ROWPASS>
__global__ __launch_bounds__(256) void k_attn_mfma(
    const u16* __restrict__ Pq, const u16* __restrict__ Pk, const u16* __restrict__ Pv,
    const float* __restrict__ biasT, u16* __restrict__ Aout)
{
    __shared__ u16 ksm[320*32];  // [j][e], 16B-slot swizzle: slot ^= (j>>1)&3
    __shared__ u16 vt[32*320];   // [e][j'], j' = PV-permuted j, slot swizzle: slot ^= e&7
    const int h = blockIdx.x, r = blockIdx.y;
    const int tid = threadIdx.x;

    const u16* Kh = Pk + (size_t)h*NP*32;
    const u16* Vh = Pv + (size_t)h*NP*32;
    const u16* Qh = Pq + (size_t)h*NP*32;

    #pragma unroll
    for (int c = 0; c < 5; ++c){
        const int flat = tid + c*256;
        const int j = flat >> 2, s = flat & 3;
        const size_t pos = ROWPASS ? ((size_t)r*NN + j) : ((size_t)j*NN + r);
        const uint4 k4 = *(const uint4*)(Kh + pos*32 + s*8);
        *(uint4*)&ksm[j*32 + ((s ^ ((j >> 1) & 3)) << 3)] = k4;
        const uint4 v4 = *(const uint4*)(Vh + pos*32 + s*8);
        union { uint4 q; u16 us[8]; } vu; vu.q = v4;
        const int jp = (j & ~31) + ((j >> 2) & 3)*8 + ((j >> 4) & 1)*4 + (j & 3);
        #pragma unroll
        for (int u = 0; u < 8; ++u){
            const int e = s*8 + u;
            vt[e*320 + (((jp >> 3) ^ (e & 7)) << 3) + (jp & 7)] = vu.us[u];
        }
    }
    __syncthreads();

    const int w = tid >> 6, l = tid & 63;
    const int li = l & 15, g = l >> 4;

    for (int t = 0; t < 5; ++t){
        const int it = w + t*4;
        const int i0 = it * 16;
        const int iq = i0 + li;
        const size_t qpos_out = ROWPASS ? ((size_t)r*NN + iq) : ((size_t)iq*NN + r);
        const short8 qf = *(const short8*)(Qh + ((size_t)r*NN + iq)*32 + g*8);  // row-style (TRQ)

        float mrun = -3.0e38f;
        float rsum = 0.f;
        f32x4 o0 = {0.f,0.f,0.f,0.f}, o1 = {0.f,0.f,0.f,0.f};

        #pragma unroll
        for (int ch = 0; ch < 2; ++ch){
            f32x4 st[10];
            const float* bp = biasT + ((((size_t)h*20 + it)*2 + ch)*10)*256 + g*64 + li*4;
            #pragma unroll
            for (int jt = 0; jt < 10; ++jt)
                st[jt] = *(const f32x4*)(bp + jt*256);

            #pragma unroll
            for (int jt = 0; jt < 10; ++jt){
                const int jr = ch*160 + jt*16 + li;
                const short8 kf = *(const short8*)&ksm[jr*32 + ((g ^ ((jr >> 1) & 3)) << 3)];
                st[jt] = MFMA16(kf, qf, st[jt]);     // S[j][i=li]
            }

            float mx = -3.0e38f;
            #pragma unroll
            for (int jt = 0; jt < 10; ++jt)
                mx = fmaxf(mx, fmaxf(fmaxf(st[jt][0], st[jt][1]), fmaxf(st[jt][2], st[jt][3])));
            mx = fmaxf(mx, __shfl_xor(mx, 16));
            mx = fmaxf(mx, __shfl_xor(mx, 32));
            const float mnew = fmaxf(mrun, mx);
            const float sc = fexp2(mrun - mnew);
            #pragma unroll
            for (int q = 0; q < 4; ++q){ o0[q] *= sc; o1[q] *= sc; }
            rsum *= sc;
            mrun = mnew;

            #pragma unroll
            for (int jt = 0; jt < 10; ++jt){
                #pragma unroll
                for (int q = 0; q < 4; ++q){
                    const float e = fexp2(st[jt][q] - mrun);
                    st[jt][q] = e; rsum += e;
                }
            }

            #pragma unroll
            for (int kt = 0; kt < 5; ++kt){
                union { u32 u[4]; short8 s8; } pu;
                pu.u[0] = cvtpk(st[2*kt][0],   st[2*kt][1]);
                pu.u[1] = cvtpk(st[2*kt][2],   st[2*kt][3]);
                pu.u[2] = cvtpk(st[2*kt+1][0], st[2*kt+1][1]);
                pu.u[3] = cvtpk(st[2*kt+1][2], st[2*kt+1][3]);
                const int ktg = ch*5 + kt;
                const int slot = ((ktg*4 + g) ^ (li & 7)) << 3;
                const short8 v0 = *(const short8*)&vt[li*320 + slot];
                const short8 v1 = *(const short8*)&vt[(16+li)*320 + slot];
                o0 = MFMA16(v0, pu.s8, o0);
                o1 = MFMA16(v1, pu.s8, o1);
            }
        }

        rsum += __shfl_xor(rsum, 16);
        rsum += __shfl_xor(rsum, 32);
        const float inv = frcp(rsum);

        u16* dst = Aout + qpos_out*DD + h*DHH;
        #pragma unroll
        for (int et = 0; et < 2; ++et){
            const f32x4 oo = et ? o1 : o0;
            uint2 o;
            o.x = cvtpk(oo[0]*inv, oo[1]*inv);
            o.y = cvtpk(oo[2]*inv, oo[3]*inv);
            *(uint2*)(dst + et*16 + g*4) = o;
        }
    }
}

// ---------------- host-side launch ----------------
extern "C" void kernel_launch(void* const* d_in, const int* in_sizes, int n_in,
                              void* d_out, int out_size, void* d_ws, size_t ws_size,
                              hipStream_t stream)
{
    const float* x = (const float*)d_in[0];
    float* out = (float*)d_out;
    char* ws = (char*)d_ws;

    u16*   Aatt  = (u16*)ws;                                  // [pos][128] bf16
    float* biasT = (float*)(ws + (size_t)NP*DD*2);            // NH*NP f32, attn-tiled
    u16*   Pq    = (u16*)(ws + (size_t)NP*DD*2 + (size_t)NH*NP*4);  // [h][pos][32]
    u16*   Pk    = Pq + (size_t)NP*DD;
    u16*   Pv    = Pk + (size_t)NP*DD;
    u16*   Pg    = Pv + (size_t)NP*DD;                        // [pos][128]
    u16*   Wpck  = Pg + (size_t)NP*DD;                        // 10*2048*8 bf16 (swizzled)

    {
        const float* w0 = (const float*)d_in[4];               // o_wq
        const float* w1 = (const float*)d_in[5];               // o_wkv (K rows)
        const float* w2 = (const float*)d_in[5] + DD*DD;       // o_wkv (V rows)
        const float* w3 = (const float*)d_in[6];               // o_wg
        const float* w4 = (const float*)d_in[8];               // o_wo
        const float* w5 = (const float*)d_in[13];              // i_wq
        const float* w6 = (const float*)d_in[14];              // i_wkv (K rows)
        const float* w7 = (const float*)d_in[14] + DD*DD;      // i_wkv (V rows)
        const float* w8 = (const float*)d_in[15];              // i_wg
        const float* w9 = (const float*)d_in[17];              // i_wo
        k_pack<<<80, 256, 0, stream>>>(w0,w1,w2,w3,w4,w5,w6,w7,w8,w9, Wpck);
    }

    for (int pass = 0; pass < 2; ++pass){
        void* const* W = d_in + 1 + pass*9;
        const float* ng = (const float*)W[0];
        const float* nb = (const float*)W[1];
        const float* wb = (const float*)W[2];
        const float* bg = (const float*)W[6];
        const float* bo = (const float*)W[8];
        const float* xin = (pass == 0) ? x : out;
        const u16* Wp = Wpck + (size_t)pass*5*2048*8;

        if (pass == 0){
            k_lnqkvg<0><<<NP/128, 256, 0, stream>>>(xin, ng, nb, wb, Wp, bg, biasT, Pq, Pk, Pv, Pg);
            k_attn_mfma<1><<<dim3(NH, NN), 256, 0, stream>>>(Pq, Pk, Pv, biasT, Aatt);
        } else {
            k_lnqkvg<1><<<NP/128, 256, 0, stream>>>(xin, ng, nb, wb, Wp, bg, biasT, Pq, Pk, Pv, Pg);
            k_attn_mfma<0><<<dim3(NH, NN), 256, 0, stream>>>(Pq, Pk, Pv, biasT, Aatt);
        }
        k_oproj<<<NP/128, 256, 0, stream>>>(Aatt, Pg, Wp, out, bo, xin);
    }
}

// Round 16
// 266.397 us; speedup vs baseline: 1.4733x; 1.0088x over previous
//
#include <hip/hip_runtime.h>
#include <hip/hip_bf16.h>

typedef unsigned short u16;
typedef unsigned int   u32;
typedef __attribute__((ext_vector_type(8))) short short8;
typedef __attribute__((ext_vector_type(4))) float f32x4;

#define NN 320
#define NP (NN*NN)
#define DD 128
#define NH 4
#define DHH 32
#define QSCALE 0.17677669529663687f
#define LOG2E  1.4426950408889634f

#define MFMA16(A,B,C) __builtin_amdgcn_mfma_f32_16x16x32_bf16(A,B,C,0,0,0)

__device__ __forceinline__ float b2f(u16 u){
    union { u32 i; float f; } v; v.i = ((u32)u) << 16; return v.f;
}
__device__ __forceinline__ u16 f2b(float f){
    union { float f; u32 i; } v; v.f = f;
    u32 x = v.i;
    u32 r = x + 0x7fffu + ((x >> 16) & 1u);
    return (u16)(r >> 16);
}
__device__ __forceinline__ u32 cvtpk(float lo, float hi){
    u32 r; asm("v_cvt_pk_bf16_f32 %0, %1, %2" : "=v"(r) : "v"(lo), "v"(hi)); return r;
}
__device__ __forceinline__ float fexp2(float x){
    float r; asm("v_exp_f32 %0, %1" : "=v"(r) : "v"(x)); return r;
}
__device__ __forceinline__ float frcp(float x){
    float r; asm("v_rcp_f32 %0, %1" : "=v"(r) : "v"(x)); return r;
}
// async global->LDS, 16B per lane; LDS dest must be wave-uniform base + lane*16
__device__ __forceinline__ void gld_lds16(const u16* gp, u16* lp){
    __builtin_amdgcn_global_load_lds(
        (const __attribute__((address_space(1))) unsigned int*)gp,
        (__attribute__((address_space(3))) unsigned int*)lp, 16, 0, 0);
}

// ---------------- Weight pre-pack: f32 [e][k] -> bf16, 16-slot swizzled ----------------
__global__ __launch_bounds__(256) void k_pack(
    const float* w0, const float* w1, const float* w2, const float* w3, const float* w4,
    const float* w5, const float* w6, const float* w7, const float* w8, const float* w9,
    u16* __restrict__ Wp)
{
    const int m = blockIdx.x >> 3;
    const int rem = ((blockIdx.x & 7) << 8) + threadIdx.x;   // 0..2047 = e*16 + slot
    const float* src;
    switch(m){
        case 0: src=w0; break; case 1: src=w1; break; case 2: src=w2; break;
        case 3: src=w3; break; case 4: src=w4; break; case 5: src=w5; break;
        case 6: src=w6; break; case 7: src=w7; break; case 8: src=w8; break;
        default: src=w9; break;
    }
    const float4 a = *(const float4*)(src + (size_t)rem*8);
    const float4 b = *(const float4*)(src + (size_t)rem*8 + 4);
    union { uint4 q; u16 us[8]; } ww;
    ww.us[0]=f2b(a.x); ww.us[1]=f2b(a.y); ww.us[2]=f2b(a.z); ww.us[3]=f2b(a.w);
    ww.us[4]=f2b(b.x); ww.us[5]=f2b(b.y); ww.us[6]=f2b(b.z); ww.us[7]=f2b(b.w);
    const int e = rem >> 4, slot = rem & 15;
    const int dst = (e << 4) + (slot ^ (e & 15));
    *(uint4*)(Wp + ((size_t)m*2048 + dst)*8) = ww.q;
}

// ---------------- Fused LN + edge-bias + QKVG GEMM (Ws via global_load_lds) ------------
template<int TRQ>
__global__ __launch_bounds__(256) void k_lnqkvg(
    const float* __restrict__ xin, const float* __restrict__ ng, const float* __restrict__ nb,
    const float* __restrict__ wb, const u16* __restrict__ Wp, const float* __restrict__ bg,
    float* __restrict__ biasT,
    u16* __restrict__ Pq, u16* __restrict__ Pk, u16* __restrict__ Pv, u16* __restrict__ Pg)
{
    __shared__ u16 As[128*128];   // 32 KB, 16B-slot swizzle: slot ^= row&7
    __shared__ u16 Ws[128*128];   // 32 KB, one phase's W tile (pre-swizzled layout)
    const int tid = threadIdx.x;
    const int pbase = blockIdx.x * 128;
    const int s  = tid & 15;
    const int d0 = s * 8;

    // prestage Ws(0) via async DMA: issues before the prologue, drains at first barrier
    #pragma unroll
    for (int c = 0; c < 8; ++c){
        const int flat = tid + c*256;
        gld_lds16(Wp + (size_t)flat*8, &Ws[flat*8]);
    }

    const float4 g0 = *(const float4*)(ng + d0), g1 = *(const float4*)(ng + d0 + 4);
    const float4 b0 = *(const float4*)(nb + d0), b1 = *(const float4*)(nb + d0 + 4);

    #pragma unroll
    for (int c = 0; c < 8; ++c){
        const int row = (tid >> 4) + c*16;
        const int p = pbase + row;
        const float* xr = xin + (size_t)p*DD + d0;
        const float4 xa = *(const float4*)xr, xb = *(const float4*)(xr + 4);
        const float xs[8] = {xa.x,xa.y,xa.z,xa.w,xb.x,xb.y,xb.z,xb.w};
        float sum = 0.f, sq = 0.f;
        #pragma unroll
        for (int u = 0; u < 8; ++u){ sum += xs[u]; sq += xs[u]*xs[u]; }
        #pragma unroll
        for (int m = 1; m < 16; m <<= 1){
            sum += __shfl_xor(sum, m);
            sq  += __shfl_xor(sq,  m);
        }
        const float mu = sum * (1.f/128.f);
        const float var = fmaxf(sq * (1.f/128.f) - mu*mu, 0.f);
        const float rstd = rsqrtf(var + 1e-5f);
        const float gg[8] = {g0.x,g0.y,g0.z,g0.w,g1.x,g1.y,g1.z,g1.w};
        const float bbv[8]= {b0.x,b0.y,b0.z,b0.w,b1.x,b1.y,b1.z,b1.w};
        float y[8];
        #pragma unroll
        for (int u = 0; u < 8; ++u) y[u] = (xs[u]-mu)*rstd*gg[u] + bbv[u];
        uint4 o;
        o.x = cvtpk(y[0],y[1]); o.y = cvtpk(y[2],y[3]);
        o.z = cvtpk(y[4],y[5]); o.w = cvtpk(y[6],y[7]);
        *(uint4*)&As[row*128 + ((s ^ (row & 7)) << 3)] = o;

        float bh0=0.f, bh1=0.f, bh2=0.f, bh3=0.f;
        {
            const float4 wa = *(const float4*)(wb + 0*DD + d0), wv2 = *(const float4*)(wb + 0*DD + d0 + 4);
            const float wv[8] = {wa.x,wa.y,wa.z,wa.w,wv2.x,wv2.y,wv2.z,wv2.w};
            #pragma unroll
            for (int u = 0; u < 8; ++u) bh0 += xs[u]*wv[u];
        }
        {
            const float4 wa = *(const float4*)(wb + 1*DD + d0), wv2 = *(const float4*)(wb + 1*DD + d0 + 4);
            const float wv[8] = {wa.x,wa.y,wa.z,wa.w,wv2.x,wv2.y,wv2.z,wv2.w};
            #pragma unroll
            for (int u = 0; u < 8; ++u) bh1 += xs[u]*wv[u];
        }
        {
            const float4 wa = *(const float4*)(wb + 2*DD + d0), wv2 = *(const float4*)(wb + 2*DD + d0 + 4);
            const float wv[8] = {wa.x,wa.y,wa.z,wa.w,wv2.x,wv2.y,wv2.z,wv2.w};
            #pragma unroll
            for (int u = 0; u < 8; ++u) bh2 += xs[u]*wv[u];
        }
        {
            const float4 wa = *(const float4*)(wb + 3*DD + d0), wv2 = *(const float4*)(wb + 3*DD + d0 + 4);
            const float wv[8] = {wa.x,wa.y,wa.z,wa.w,wv2.x,wv2.y,wv2.z,wv2.w};
            #pragma unroll
            for (int u = 0; u < 8; ++u) bh3 += xs[u]*wv[u];
        }
        #pragma unroll
        for (int m = 1; m < 16; m <<= 1){
            bh0 += __shfl_xor(bh0, m); bh1 += __shfl_xor(bh1, m);
            bh2 += __shfl_xor(bh2, m); bh3 += __shfl_xor(bh3, m);
        }
        if (s < 4){
            const float bsel = (s == 0) ? bh0 : (s == 1) ? bh1 : (s == 2) ? bh2 : bh3;
            const int pi = p / NN, pj = p - pi*NN;
            const int it = pi >> 4, lb = pi & 15;
            const int ch = (pj >= 160) ? 1 : 0;
            const int jj = pj - ch*160;
            const int jt = jj >> 4, rr = jj & 15;
            const int gb = rr >> 2, qb = rr & 3;
            const size_t idx = (((((size_t)s*20 + it)*2 + ch)*10 + jt)*4 + gb)*64 + lb*4 + qb;
            biasT[idx] = bsel * LOG2E;
        }
    }

    const int w = tid >> 6, l = tid & 63;
    const int li = l & 15, g = l >> 4;
    const int wr = w >> 1, wc = w & 1;

    #pragma unroll
    for (int p = 0; p < 4; ++p){
        if (p > 0){
            __syncthreads();                 // drain Ws(p-1) reads
            #pragma unroll
            for (int c = 0; c < 8; ++c){
                const int flat = tid + c*256;
                gld_lds16(Wp + ((size_t)p*2048 + flat)*8, &Ws[flat*8]);
            }
        }
        __syncthreads();                     // Ws(p) DMA drained (p==0: As+Ws0 ready)

        f32x4 acc[4][4] = {};
        #pragma unroll
        for (int ks = 0; ks < 4; ++ks){
            const int slot = ks*4 + g;
            short8 af[4];
            #pragma unroll
            for (int mt = 0; mt < 4; ++mt){
                const int row = wr*64 + mt*16 + li;
                af[mt] = *(const short8*)&As[row*128 + ((slot ^ (row & 7)) << 3)];
            }
            #pragma unroll
            for (int nt = 0; nt < 4; ++nt){
                const int e = wc*64 + nt*16 + li;
                const short8 wf = *(const short8*)&Ws[((e << 4) + (slot ^ (e & 15))) * 8];
                #pragma unroll
                for (int mt = 0; mt < 4; ++mt)
                    acc[mt][nt] = MFMA16(wf, af[mt], acc[mt][nt]);   // D[e][pos]
            }
        }

        u16* Op = (p == 0) ? Pq : (p == 1) ? Pk : (p == 2) ? Pv : Pg;
        #pragma unroll
        for (int mt = 0; mt < 4; ++mt){
            const int pos = pbase + wr*64 + mt*16 + li;
            int ps = pos;
            if (TRQ && p == 0){                      // transpose Q only
                const int pi = pos / NN, pj = pos - pi*NN;
                ps = pj*NN + pi;
            }
            #pragma unroll
            for (int nt = 0; nt < 4; ++nt){
                const int eb = wc*64 + nt*16 + g*4;
                float v[4];
                #pragma unroll
                for (int q = 0; q < 4; ++q) v[q] = acc[mt][nt][q];
                if (p == 0){
                    #pragma unroll
                    for (int q = 0; q < 4; ++q) v[q] *= (QSCALE * LOG2E);
                } else if (p == 3){
                    #pragma unroll
                    for (int q = 0; q < 4; ++q) v[q] = frcp(1.f + fexp2(-LOG2E*(v[q] + bg[eb+q])));
                }
                uint2 o;
                o.x = cvtpk(v[0], v[1]);
                o.y = cvtpk(v[2], v[3]);
                if (p < 3){
                    u16* dst = Op + ((size_t)(eb >> 5)*NP + ps)*32 + (eb & 31);
                    *(uint2*)dst = o;
                } else {
                    *(uint2*)(Pg + (size_t)pos*DD + eb) = o;
                }
            }
        }
    }
}

// ---------------- Output projection (gated staging; Ws via global_load_lds) ------------
__global__ __launch_bounds__(256) void k_oproj(
    const u16* __restrict__ Aatt, const u16* __restrict__ Pg, const u16* __restrict__ Wp,
    float* __restrict__ Outp, const float* __restrict__ bov, const float* __restrict__ xres)
{
    __shared__ u16 As[128*128];
    __shared__ u16 Ws[128*128];
    const int tid = threadIdx.x;
    const int pbase = blockIdx.x * 128;

    // async Ws DMA first: streams while the gated A-staging computes
    #pragma unroll
    for (int c = 0; c < 8; ++c){
        const int flat = tid + c*256;
        gld_lds16(Wp + ((size_t)4*2048 + flat)*8, &Ws[flat*8]);
    }

    #pragma unroll
    for (int c = 0; c < 8; ++c){
        const int flat = tid + c*256;
        const int row = flat >> 4, s = flat & 15;
        const size_t off = (size_t)(pbase+row)*DD + s*8;
        union { uint4 q; u16 us[8]; } ua, ug;
        ua.q = *(const uint4*)(Aatt + off);
        ug.q = *(const uint4*)(Pg + off);
        uint4 o;
        o.x = cvtpk(b2f(ua.us[0])*b2f(ug.us[0]), b2f(ua.us[1])*b2f(ug.us[1]));
        o.y = cvtpk(b2f(ua.us[2])*b2f(ug.us[2]), b2f(ua.us[3])*b2f(ug.us[3]));
        o.z = cvtpk(b2f(ua.us[4])*b2f(ug.us[4]), b2f(ua.us[5])*b2f(ug.us[5]));
        o.w = cvtpk(b2f(ua.us[6])*b2f(ug.us[6]), b2f(ua.us[7])*b2f(ug.us[7]));
        *(uint4*)&As[row*128 + ((s ^ (row & 7)) << 3)] = o;
    }
    __syncthreads();

    const int w = tid >> 6, l = tid & 63;
    const int li = l & 15, g = l >> 4;
    const int wr = w >> 1, wc = w & 1;
    f32x4 acc[4][4] = {};

    #pragma unroll
    for (int ks = 0; ks < 4; ++ks){
        const int slot = ks*4 + g;
        short8 af[4];
        #pragma unroll
        for (int mt = 0; mt < 4; ++mt){
            const int row = wr*64 + mt*16 + li;
            af[mt] = *(const short8*)&As[row*128 + ((slot ^ (row & 7)) << 3)];
        }
        #pragma unroll
        for (int nt = 0; nt < 4; ++nt){
            const int e = wc*64 + nt*16 + li;
            const short8 wf = *(const short8*)&Ws[((e << 4) + (slot ^ (e & 15))) * 8];
            #pragma unroll
            for (int mt = 0; mt < 4; ++mt)
                acc[mt][nt] = MFMA16(wf, af[mt], acc[mt][nt]);   // D[d][pos]
        }
    }

    #pragma unroll
    for (int mt = 0; mt < 4; ++mt){
        const int pos = pbase + wr*64 + mt*16 + li;
        #pragma unroll
        for (int nt = 0; nt < 4; ++nt){
            const int d0 = wc*64 + nt*16 + g*4;
            const float4 xr = *(const float4*)(xres + (size_t)pos*DD + d0);
            const float4 bo4 = *(const float4*)(bov + d0);
            float4 o;
            o.x = acc[mt][nt][0] + bo4.x + xr.x;
            o.y = acc[mt][nt][1] + bo4.y + xr.y;
            o.z = acc[mt][nt][2] + bo4.z + xr.z;
            o.w = acc[mt][nt][3] + bo4.w + xr.w;
            *(float4*)(Outp + (size_t)pos*DD + d0) = o;
        }
    }
}

// ---------------- MFMA attention (r15 structure + s_setprio around MFMA clusters) ------
template<int ROWPASS>
__global__ __launch_bounds__(256) void k_attn_mfma(
    const u16* __restrict__ Pq, const u16* __restrict__ Pk, const u16* __restrict__ Pv,
    const float* __restrict__ biasT, u16* __restrict__ Aout)
{
    __shared__ u16 ksm[320*32];  // [j][e], 16B-slot swizzle: slot ^= (j>>1)&3
    __shared__ u16 vt[32*320];   // [e][j'], j' = PV-permuted j, slot swizzle: slot ^= e&7
    const int h = blockIdx.x, r = blockIdx.y;
    const int tid = threadIdx.x;

    const u16* Kh = Pk + (size_t)h*NP*32;
    const u16* Vh = Pv + (size_t)h*NP*32;
    const u16* Qh = Pq + (size_t)h*NP*32;

    #pragma unroll
    for (int c = 0; c < 5; ++c){
        const int flat = tid + c*256;
        const int j = flat >> 2, s = flat & 3;
        const size_t pos = ROWPASS ? ((size_t)r*NN + j) : ((size_t)j*NN + r);
        const uint4 k4 = *(const uint4*)(Kh + pos*32 + s*8);
        *(uint4*)&ksm[j*32 + ((s ^ ((j >> 1) & 3)) << 3)] = k4;
        const uint4 v4 = *(const uint4*)(Vh + pos*32 + s*8);
        union { uint4 q; u16 us[8]; } vu; vu.q = v4;
        const int jp = (j & ~31) + ((j >> 2) & 3)*8 + ((j >> 4) & 1)*4 + (j & 3);
        #pragma unroll
        for (int u = 0; u < 8; ++u){
            const int e = s*8 + u;
            vt[e*320 + (((jp >> 3) ^ (e & 7)) << 3) + (jp & 7)] = vu.us[u];
        }
    }
    __syncthreads();

    const int w = tid >> 6, l = tid & 63;
    const int li = l & 15, g = l >> 4;

    for (int t = 0; t < 5; ++t){
        const int it = w + t*4;
        const int i0 = it * 16;
        const int iq = i0 + li;
        const size_t qpos_out = ROWPASS ? ((size_t)r*NN + iq) : ((size_t)iq*NN + r);
        const short8 qf = *(const short8*)(Qh + ((size_t)r*NN + iq)*32 + g*8);  // row-style (TRQ)

        float mrun = -3.0e38f;
        float rsum = 0.f;
        f32x4 o0 = {0.f,0.f,0.f,0.f}, o1 = {0.f,0.f,0.f,0.f};

        #pragma unroll
        for (int ch = 0; ch < 2; ++ch){
            f32x4 st[10];
            const float* bp = biasT + ((((size_t)h*20 + it)*2 + ch)*10)*256 + g*64 + li*4;
            #pragma unroll
            for (int jt = 0; jt < 10; ++jt)
                st[jt] = *(const f32x4*)(bp + jt*256);

            __builtin_amdgcn_s_setprio(1);
            #pragma unroll
            for (int jt = 0; jt < 10; ++jt){
                const int jr = ch*160 + jt*16 + li;
                const short8 kf = *(const short8*)&ksm[jr*32 + ((g ^ ((jr >> 1) & 3)) << 3)];
                st[jt] = MFMA16(kf, qf, st[jt]);     // S[j][i=li]
            }
            __builtin_amdgcn_s_setprio(0);

            float mx = -3.0e38f;
            #pragma unroll
            for (int jt = 0; jt < 10; ++jt)
                mx = fmaxf(mx, fmaxf(fmaxf(st[jt][0], st[jt][1]), fmaxf(st[jt][2], st[jt][3])));
            mx = fmaxf(mx, __shfl_xor(mx, 16));
            mx = fmaxf(mx, __shfl_xor(mx, 32));
            const float mnew = fmaxf(mrun, mx);
            const float sc = fexp2(mrun - mnew);
            #pragma unroll
            for (int q = 0; q < 4; ++q){ o0[q] *= sc; o1[q] *= sc; }
            rsum *= sc;
            mrun = mnew;

            #pragma unroll
            for (int jt = 0; jt < 10; ++jt){
                #pragma unroll
                for (int q = 0; q < 4; ++q){
                    const float e = fexp2(st[jt][q] - mrun);
                    st[jt][q] = e; rsum += e;
                }
            }

            __builtin_amdgcn_s_setprio(1);
            #pragma unroll
            for (int kt = 0; kt < 5; ++kt){
                union { u32 u[4]; short8 s8; } pu;
                pu.u[0] = cvtpk(st[2*kt][0],   st[2*kt][1]);
                pu.u[1] = cvtpk(st[2*kt][2],   st[2*kt][3]);
                pu.u[2] = cvtpk(st[2*kt+1][0], st[2*kt+1][1]);
                pu.u[3] = cvtpk(st[2*kt+1][2], st[2*kt+1][3]);
                const int ktg = ch*5 + kt;
                const int slot = ((ktg*4 + g) ^ (li & 7)) << 3;
                const short8 v0 = *(const short8*)&vt[li*320 + slot];
                const short8 v1 = *(const short8*)&vt[(16+li)*320 + slot];
                o0 = MFMA16(v0, pu.s8, o0);
                o1 = MFMA16(v1, pu.s8, o1);
            }
            __builtin_amdgcn_s_setprio(0);
        }

        rsum += __shfl_xor(rsum, 16);
        rsum += __shfl_xor(rsum, 32);
        const float inv = frcp(rsum);

        u16* dst = Aout + qpos_out*DD + h*DHH;
        #pragma unroll
        for (int et = 0; et < 2; ++et){
            const f32x4 oo = et ? o1 : o0;
            uint2 o;
            o.x = cvtpk(oo[0]*inv, oo[1]*inv);
            o.y = cvtpk(oo[2]*inv, oo[3]*inv);
            *(uint2*)(dst + et*16 + g*4) = o;
        }
    }
}

// ---------------- host-side launch ----------------
extern "C" void kernel_launch(void* const* d_in, const int* in_sizes, int n_in,
                              void* d_out, int out_size, void* d_ws, size_t ws_size,
                              hipStream_t stream)
{
    const float* x = (const float*)d_in[0];
    float* out = (float*)d_out;
    char* ws = (char*)d_ws;

    u16*   Aatt  = (u16*)ws;                                  // [pos][128] bf16
    float* biasT = (float*)(ws + (size_t)NP*DD*2);            // NH*NP f32, attn-tiled
    u16*   Pq    = (u16*)(ws + (size_t)NP*DD*2 + (size_t)NH*NP*4);  // [h][pos][32]
    u16*   Pk    = Pq + (size_t)NP*DD;
    u16*   Pv    = Pk + (size_t)NP*DD;
    u16*   Pg    = Pv + (size_t)NP*DD;                        // [pos][128]
    u16*   Wpck  = Pg + (size_t)NP*DD;                        // 10*2048*8 bf16 (swizzled)

    {
        const float* w0 = (const float*)d_in[4];               // o_wq
        const float* w1 = (const float*)d_in[5];               // o_wkv (K rows)
        const float* w2 = (const float*)d_in[5] + DD*DD;       // o_wkv (V rows)
        const float* w3 = (const float*)d_in[6];               // o_wg
        const float* w4 = (const float*)d_in[8];               // o_wo
        const float* w5 = (const float*)d_in[13];              // i_wq
        const float* w6 = (const float*)d_in[14];              // i_wkv (K rows)
        const float* w7 = (const float*)d_in[14] + DD*DD;      // i_wkv (V rows)
        const float* w8 = (const float*)d_in[15];              // i_wg
        const float* w9 = (const float*)d_in[17];              // i_wo
        k_pack<<<80, 256, 0, stream>>>(w0,w1,w2,w3,w4,w5,w6,w7,w8,w9, Wpck);
    }

    for (int pass = 0; pass < 2; ++pass){
        void* const* W = d_in + 1 + pass*9;
        const float* ng = (const float*)W[0];
        const float* nb = (const float*)W[1];
        const float* wb = (const float*)W[2];
        const float* bg = (const float*)W[6];
        const float* bo = (const float*)W[8];
        const float* xin = (pass == 0) ? x : out;
        const u16* Wp = Wpck + (size_t)pass*5*2048*8;

        if (pass == 0){
            k_lnqkvg<0><<<NP/128, 256, 0, stream>>>(xin, ng, nb, wb, Wp, bg, biasT, Pq, Pk, Pv, Pg);
            k_attn_mfma<1><<<dim3(NH, NN), 256, 0, stream>>>(Pq, Pk, Pv, biasT, Aatt);
        } else {
            k_lnqkvg<1><<<NP/128, 256, 0, stream>>>(xin, ng, nb, wb, Wp, bg, biasT, Pq, Pk, Pv, Pg);
            k_attn_mfma<0><<<dim3(NH, NN), 256, 0, stream>>>(Pq, Pk, Pv, biasT, Aatt);
        }
        k_oproj<<<NP/128, 256, 0, stream>>>(Aatt, Pg, Wp, out, bo, xin);
    }
}

// Round 17
// 254.212 us; speedup vs baseline: 1.5439x; 1.0479x over previous
//
#include <hip/hip_runtime.h>
#include <hip/hip_bf16.h>

typedef unsigned short u16;
typedef unsigned int   u32;
typedef __attribute__((ext_vector_type(8))) short short8;
typedef __attribute__((ext_vector_type(4))) float f32x4;

#define NN 320
#define NP (NN*NN)
#define DD 128
#define NH 4
#define DHH 32
#define QSCALE 0.17677669529663687f
#define LOG2E  1.4426950408889634f

#define MFMA16(A,B,C) __builtin_amdgcn_mfma_f32_16x16x32_bf16(A,B,C,0,0,0)

__device__ __forceinline__ float b2f(u16 u){
    union { u32 i; float f; } v; v.i = ((u32)u) << 16; return v.f;
}
__device__ __forceinline__ u16 f2b(float f){
    union { float f; u32 i; } v; v.f = f;
    u32 x = v.i;
    u32 r = x + 0x7fffu + ((x >> 16) & 1u);
    return (u16)(r >> 16);
}
__device__ __forceinline__ u32 cvtpk(float lo, float hi){
    u32 r; asm("v_cvt_pk_bf16_f32 %0, %1, %2" : "=v"(r) : "v"(lo), "v"(hi)); return r;
}
__device__ __forceinline__ float fexp2(float x){
    float r; asm("v_exp_f32 %0, %1" : "=v"(r) : "v"(x)); return r;
}
__device__ __forceinline__ float frcp(float x){
    float r; asm("v_rcp_f32 %0, %1" : "=v"(r) : "v"(x)); return r;
}
// async global->LDS, 16B per lane; LDS dest must be wave-uniform base + lane*16
__device__ __forceinline__ void gld_lds16(const u16* gp, u16* lp){
    __builtin_amdgcn_global_load_lds(
        (const __attribute__((address_space(1))) unsigned int*)gp,
        (__attribute__((address_space(3))) unsigned int*)lp, 16, 0, 0);
}

// ---------------- Weight pre-pack: f32 [e][k] -> bf16, 16-slot swizzled ----------------
__global__ __launch_bounds__(256) void k_pack(
    const float* w0, const float* w1, const float* w2, const float* w3, const float* w4,
    const float* w5, const float* w6, const float* w7, const float* w8, const float* w9,
    u16* __restrict__ Wp)
{
    const int m = blockIdx.x >> 3;
    const int rem = ((blockIdx.x & 7) << 8) + threadIdx.x;   // 0..2047 = e*16 + slot
    const float* src;
    switch(m){
        case 0: src=w0; break; case 1: src=w1; break; case 2: src=w2; break;
        case 3: src=w3; break; case 4: src=w4; break; case 5: src=w5; break;
        case 6: src=w6; break; case 7: src=w7; break; case 8: src=w8; break;
        default: src=w9; break;
    }
    const float4 a = *(const float4*)(src + (size_t)rem*8);
    const float4 b = *(const float4*)(src + (size_t)rem*8 + 4);
    union { uint4 q; u16 us[8]; } ww;
    ww.us[0]=f2b(a.x); ww.us[1]=f2b(a.y); ww.us[2]=f2b(a.z); ww.us[3]=f2b(a.w);
    ww.us[4]=f2b(b.x); ww.us[5]=f2b(b.y); ww.us[6]=f2b(b.z); ww.us[7]=f2b(b.w);
    const int e = rem >> 4, slot = rem & 15;
    const int dst = (e << 4) + (slot ^ (e & 15));
    *(uint4*)(Wp + ((size_t)m*2048 + dst)*8) = ww.q;
}

// ---------------- Fused LN + edge-bias + QKVG GEMM (64-row tile -> 48KB LDS, 3 blk/CU) --
// P layout: [h][pos][32]. TRQ=1 (pass 1): Q stored pos-transposed. bias: f32, tiled.
// Ws staged async (global_load_lds); barrier structure unchanged (2/phase).
template<int TRQ>
__global__ __launch_bounds__(256) void k_lnqkvg(
    const float* __restrict__ xin, const float* __restrict__ ng, const float* __restrict__ nb,
    const float* __restrict__ wb, const u16* __restrict__ Wp, const float* __restrict__ bg,
    float* __restrict__ biasT,
    u16* __restrict__ Pq, u16* __restrict__ Pk, u16* __restrict__ Pv, u16* __restrict__ Pg)
{
    __shared__ u16 As[64*128];    // 16 KB, 16B-slot swizzle: slot ^= row&7
    __shared__ u16 Ws[128*128];   // 32 KB, one phase's W tile (pre-swizzled layout)
    const int tid = threadIdx.x;
    const int pbase = blockIdx.x * 64;
    const int s  = tid & 15;
    const int d0 = s * 8;

    // prestage Ws(0) via async DMA: issues before the prologue, drains at first barrier
    #pragma unroll
    for (int c = 0; c < 8; ++c){
        const int flat = tid + c*256;
        gld_lds16(Wp + (size_t)flat*8, &Ws[flat*8]);
    }

    const float4 g0 = *(const float4*)(ng + d0), g1 = *(const float4*)(ng + d0 + 4);
    const float4 b0 = *(const float4*)(nb + d0), b1 = *(const float4*)(nb + d0 + 4);

    #pragma unroll
    for (int c = 0; c < 4; ++c){
        const int row = (tid >> 4) + c*16;
        const int p = pbase + row;
        const float* xr = xin + (size_t)p*DD + d0;
        const float4 xa = *(const float4*)xr, xb = *(const float4*)(xr + 4);
        const float xs[8] = {xa.x,xa.y,xa.z,xa.w,xb.x,xb.y,xb.z,xb.w};
        float sum = 0.f, sq = 0.f;
        #pragma unroll
        for (int u = 0; u < 8; ++u){ sum += xs[u]; sq += xs[u]*xs[u]; }
        #pragma unroll
        for (int m = 1; m < 16; m <<= 1){
            sum += __shfl_xor(sum, m);
            sq  += __shfl_xor(sq,  m);
        }
        const float mu = sum * (1.f/128.f);
        const float var = fmaxf(sq * (1.f/128.f) - mu*mu, 0.f);
        const float rstd = rsqrtf(var + 1e-5f);
        const float gg[8] = {g0.x,g0.y,g0.z,g0.w,g1.x,g1.y,g1.z,g1.w};
        const float bbv[8]= {b0.x,b0.y,b0.z,b0.w,b1.x,b1.y,b1.z,b1.w};
        float y[8];
        #pragma unroll
        for (int u = 0; u < 8; ++u) y[u] = (xs[u]-mu)*rstd*gg[u] + bbv[u];
        uint4 o;
        o.x = cvtpk(y[0],y[1]); o.y = cvtpk(y[2],y[3]);
        o.z = cvtpk(y[4],y[5]); o.w = cvtpk(y[6],y[7]);
        *(uint4*)&As[row*128 + ((s ^ (row & 7)) << 3)] = o;

        float bh0=0.f, bh1=0.f, bh2=0.f, bh3=0.f;
        {
            const float4 wa = *(const float4*)(wb + 0*DD + d0), wv2 = *(const float4*)(wb + 0*DD + d0 + 4);
            const float wv[8] = {wa.x,wa.y,wa.z,wa.w,wv2.x,wv2.y,wv2.z,wv2.w};
            #pragma unroll
            for (int u = 0; u < 8; ++u) bh0 += xs[u]*wv[u];
        }
        {
            const float4 wa = *(const float4*)(wb + 1*DD + d0), wv2 = *(const float4*)(wb + 1*DD + d0 + 4);
            const float wv[8] = {wa.x,wa.y,wa.z,wa.w,wv2.x,wv2.y,wv2.z,wv2.w};
            #pragma unroll
            for (int u = 0; u < 8; ++u) bh1 += xs[u]*wv[u];
        }
        {
            const float4 wa = *(const float4*)(wb + 2*DD + d0), wv2 = *(const float4*)(wb + 2*DD + d0 + 4);
            const float wv[8] = {wa.x,wa.y,wa.z,wa.w,wv2.x,wv2.y,wv2.z,wv2.w};
            #pragma unroll
            for (int u = 0; u < 8; ++u) bh2 += xs[u]*wv[u];
        }
        {
            const float4 wa = *(const float4*)(wb + 3*DD + d0), wv2 = *(const float4*)(wb + 3*DD + d0 + 4);
            const float wv[8] = {wa.x,wa.y,wa.z,wa.w,wv2.x,wv2.y,wv2.z,wv2.w};
            #pragma unroll
            for (int u = 0; u < 8; ++u) bh3 += xs[u]*wv[u];
        }
        #pragma unroll
        for (int m = 1; m < 16; m <<= 1){
            bh0 += __shfl_xor(bh0, m); bh1 += __shfl_xor(bh1, m);
            bh2 += __shfl_xor(bh2, m); bh3 += __shfl_xor(bh3, m);
        }
        if (s < 4){
            const float bsel = (s == 0) ? bh0 : (s == 1) ? bh1 : (s == 2) ? bh2 : bh3;
            const int pi = p / NN, pj = p - pi*NN;
            const int it = pi >> 4, lb = pi & 15;
            const int ch = (pj >= 160) ? 1 : 0;
            const int jj = pj - ch*160;
            const int jt = jj >> 4, rr = jj & 15;
            const int gb = rr >> 2, qb = rr & 3;
            const size_t idx = (((((size_t)s*20 + it)*2 + ch)*10 + jt)*4 + gb)*64 + lb*4 + qb;
            biasT[idx] = bsel * LOG2E;
        }
    }

    const int w = tid >> 6, l = tid & 63;
    const int li = l & 15, g = l >> 4;
    const int wr = w >> 1, wc = w & 1;

    #pragma unroll
    for (int p = 0; p < 4; ++p){
        if (p > 0){
            __syncthreads();                 // drain Ws(p-1) reads
            #pragma unroll
            for (int c = 0; c < 8; ++c){
                const int flat = tid + c*256;
                gld_lds16(Wp + ((size_t)p*2048 + flat)*8, &Ws[flat*8]);
            }
        }
        __syncthreads();                     // Ws(p) DMA drained (p==0: As+Ws0 ready)

        f32x4 acc[2][4] = {};
        #pragma unroll
        for (int ks = 0; ks < 4; ++ks){
            const int slot = ks*4 + g;
            short8 af[2];
            #pragma unroll
            for (int mt = 0; mt < 2; ++mt){
                const int row = wr*32 + mt*16 + li;
                af[mt] = *(const short8*)&As[row*128 + ((slot ^ (row & 7)) << 3)];
            }
            #pragma unroll
            for (int nt = 0; nt < 4; ++nt){
                const int e = wc*64 + nt*16 + li;
                const short8 wf = *(const short8*)&Ws[((e << 4) + (slot ^ (e & 15))) * 8];
                #pragma unroll
                for (int mt = 0; mt < 2; ++mt)
                    acc[mt][nt] = MFMA16(wf, af[mt], acc[mt][nt]);   // D[e][pos]
            }
        }

        u16* Op = (p == 0) ? Pq : (p == 1) ? Pk : (p == 2) ? Pv : Pg;
        #pragma unroll
        for (int mt = 0; mt < 2; ++mt){
            const int pos = pbase + wr*32 + mt*16 + li;
            int ps = pos;
            if (TRQ && p == 0){                      // transpose Q only
                const int pi = pos / NN, pj = pos - pi*NN;
                ps = pj*NN + pi;
            }
            #pragma unroll
            for (int nt = 0; nt < 4; ++nt){
                const int eb = wc*64 + nt*16 + g*4;
                float v[4];
                #pragma unroll
                for (int q = 0; q < 4; ++q) v[q] = acc[mt][nt][q];
                if (p == 0){
                    #pragma unroll
                    for (int q = 0; q < 4; ++q) v[q] *= (QSCALE * LOG2E);
                } else if (p == 3){
                    #pragma unroll
                    for (int q = 0; q < 4; ++q) v[q] = frcp(1.f + fexp2(-LOG2E*(v[q] + bg[eb+q])));
                }
                uint2 o;
                o.x = cvtpk(v[0], v[1]);
                o.y = cvtpk(v[2], v[3]);
                if (p < 3){
                    u16* dst = Op + ((size_t)(eb >> 5)*NP + ps)*32 + (eb & 31);
                    *(uint2*)dst = o;
                } else {
                    *(uint2*)(Pg + (size_t)pos*DD + eb) = o;
                }
            }
        }
    }
}

// ---------------- Output projection (gated staging; Ws via global_load_lds) ------------
__global__ __launch_bounds__(256) void k_oproj(
    const u16* __restrict__ Aatt, const u16* __restrict__ Pg, const u16* __restrict__ Wp,
    float* __restrict__ Outp, const float* __restrict__ bov, const float* __restrict__ xres)
{
    __shared__ u16 As[128*128];
    __shared__ u16 Ws[128*128];
    const int tid = threadIdx.x;
    const int pbase = blockIdx.x * 128;

    // async Ws DMA first: streams while the gated A-staging computes
    #pragma unroll
    for (int c = 0; c < 8; ++c){
        const int flat = tid + c*256;
        gld_lds16(Wp + ((size_t)4*2048 + flat)*8, &Ws[flat*8]);
    }

    #pragma unroll
    for (int c = 0; c < 8; ++c){
        const int flat = tid + c*256;
        const int row = flat >> 4, s = flat & 15;
        const size_t off = (size_t)(pbase+row)*DD + s*8;
        union { uint4 q; u16 us[8]; } ua, ug;
        ua.q = *(const uint4*)(Aatt + off);
        ug.q = *(const uint4*)(Pg + off);
        uint4 o;
        o.x = cvtpk(b2f(ua.us[0])*b2f(ug.us[0]), b2f(ua.us[1])*b2f(ug.us[1]));
        o.y = cvtpk(b2f(ua.us[2])*b2f(ug.us[2]), b2f(ua.us[3])*b2f(ug.us[3]));
        o.z = cvtpk(b2f(ua.us[4])*b2f(ug.us[4]), b2f(ua.us[5])*b2f(ug.us[5]));
        o.w = cvtpk(b2f(ua.us[6])*b2f(ug.us[6]), b2f(ua.us[7])*b2f(ug.us[7]));
        *(uint4*)&As[row*128 + ((s ^ (row & 7)) << 3)] = o;
    }
    __syncthreads();

    const int w = tid >> 6, l = tid & 63;
    const int li = l & 15, g = l >> 4;
    const int wr = w >> 1, wc = w & 1;
    f32x4 acc[4][4] = {};

    #pragma unroll
    for (int ks = 0; ks < 4; ++ks){
        const int slot = ks*4 + g;
        short8 af[4];
        #pragma unroll
        for (int mt = 0; mt < 4; ++mt){
            const int row = wr*64 + mt*16 + li;
            af[mt] = *(const short8*)&As[row*128 + ((slot ^ (row & 7)) << 3)];
        }
        #pragma unroll
        for (int nt = 0; nt < 4; ++nt){
            const int e = wc*64 + nt*16 + li;
            const short8 wf = *(const short8*)&Ws[((e << 4) + (slot ^ (e & 15))) * 8];
            #pragma unroll
            for (int mt = 0; mt < 4; ++mt)
                acc[mt][nt] = MFMA16(wf, af[mt], acc[mt][nt]);   // D[d][pos]
        }
    }

    #pragma unroll
    for (int mt = 0; mt < 4; ++mt){
        const int pos = pbase + wr*64 + mt*16 + li;
        #pragma unroll
        for (int nt = 0; nt < 4; ++nt){
            const int d0 = wc*64 + nt*16 + g*4;
            const float4 xr = *(const float4*)(xres + (size_t)pos*DD + d0);
            const float4 bo4 = *(const float4*)(bov + d0);
            float4 o;
            o.x = acc[mt][nt][0] + bo4.x + xr.x;
            o.y = acc[mt][nt][1] + bo4.y + xr.y;
            o.z = acc[mt][nt][2] + bo4.z + xr.z;
            o.w = acc[mt][nt][3] + bo4.w + xr.w;
            *(float4*)(Outp + (size_t)pos*DD + d0) = o;
        }
    }
}

// ---------------- MFMA attention (r16 structure: setprio around MFMA clusters) ---------
template<int ROWPASS>
__global__ __launch_bounds__(256) void k_attn_mfma(
    const u16* __restrict__ Pq, const u16* __restrict__ Pk, const u16* __restrict__ Pv,
    const float* __restrict__ biasT, u16* __restrict__ Aout)
{
    __shared__ u16 ksm[320*32];  // [j][e], 16B-slot swizzle: slot ^= (j>>1)&3
    __shared__ u16 vt[32*320];   // [e][j'], j' = PV-permuted j, slot swizzle: slot ^= e&7
    const int h = blockIdx.x, r = blockIdx.y;
    const int tid = threadIdx.x;

    const u16* Kh = Pk + (size_t)h*NP*32;
    const u16* Vh = Pv + (size_t)h*NP*32;
    const u16* Qh = Pq + (size_t)h*NP*32;

    #pragma unroll
    for (int c = 0; c < 5; ++c){
        const int flat = tid + c*256;
        const int j = flat >> 2, s = flat & 3;
        const size_t pos = ROWPASS ? ((size_t)r*NN + j) : ((size_t)j*NN + r);
        const uint4 k4 = *(const uint4*)(Kh + pos*32 + s*8);
        *(uint4*)&ksm[j*32 + ((s ^ ((j >> 1) & 3)) << 3)] = k4;
        const uint4 v4 = *(const uint4*)(Vh + pos*32 + s*8);
        union { uint4 q; u16 us[8]; } vu; vu.q = v4;
        const int jp = (j & ~31) + ((j >> 2) & 3)*8 + ((j >> 4) & 1)*4 + (j & 3);
        #pragma unroll
        for (int u = 0; u < 8; ++u){
            const int e = s*8 + u;
            vt[e*320 + (((jp >> 3) ^ (e & 7)) << 3) + (jp & 7)] = vu.us[u];
        }
    }
    __syncthreads();

    const int w = tid >> 6, l = tid & 63;
    const int li = l & 15, g = l >> 4;

    for (int t = 0; t < 5; ++t){
        const int it = w + t*4;
        const int i0 = it * 16;
        const int iq = i0 + li;
        const size_t qpos_out = ROWPASS ? ((size_t)r*NN + iq) : ((size_t)iq*NN + r);
        const short8 qf = *(const short8*)(Qh + ((size_t)r*NN + iq)*32 + g*8);  // row-style (TRQ)

        float mrun = -3.0e38f;
        float rsum = 0.f;
        f32x4 o0 = {0.f,0.f,0.f,0.f}, o1 = {0.f,0.f,0.f,0.f};

        #pragma unroll
        for (int ch = 0; ch < 2; ++ch){
            f32x4 st[10];
            const float* bp = biasT + ((((size_t)h*20 + it)*2 + ch)*10)*256 + g*64 + li*4;
            #pragma unroll
            for (int jt = 0; jt < 10; ++jt)
                st[jt] = *(const f32x4*)(bp + jt*256);

            __builtin_amdgcn_s_setprio(1);
            #pragma unroll
            for (int jt = 0; jt < 10; ++jt){
                const int jr = ch*160 + jt*16 + li;
                const short8 kf = *(const short8*)&ksm[jr*32 + ((g ^ ((jr >> 1) & 3)) << 3)];
                st[jt] = MFMA16(kf, qf, st[jt]);     // S[j][i=li]
            }
            __builtin_amdgcn_s_setprio(0);

            float mx = -3.0e38f;
            #pragma unroll
            for (int jt = 0; jt < 10; ++jt)
                mx = fmaxf(mx, fmaxf(fmaxf(st[jt][0], st[jt][1]), fmaxf(st[jt][2], st[jt][3])));
            mx = fmaxf(mx, __shfl_xor(mx, 16));
            mx = fmaxf(mx, __shfl_xor(mx, 32));
            const float mnew = fmaxf(mrun, mx);
            const float sc = fexp2(mrun - mnew);
            #pragma unroll
            for (int q = 0; q < 4; ++q){ o0[q] *= sc; o1[q] *= sc; }
            rsum *= sc;
            mrun = mnew;

            #pragma unroll
            for (int jt = 0; jt < 10; ++jt){
                #pragma unroll
                for (int q = 0; q < 4; ++q){
                    const float e = fexp2(st[jt][q] - mrun);
                    st[jt][q] = e; rsum += e;
                }
            }

            __builtin_amdgcn_s_setprio(1);
            #pragma unroll
            for (int kt = 0; kt < 5; ++kt){
                union { u32 u[4]; short8 s8; } pu;
                pu.u[0] = cvtpk(st[2*kt][0],   st[2*kt][1]);
                pu.u[1] = cvtpk(st[2*kt][2],   st[2*kt][3]);
                pu.u[2] = cvtpk(st[2*kt+1][0], st[2*kt+1][1]);
                pu.u[3] = cvtpk(st[2*kt+1][2], st[2*kt+1][3]);
                const int ktg = ch*5 + kt;
                const int slot = ((ktg*4 + g) ^ (li & 7)) << 3;
                const short8 v0 = *(const short8*)&vt[li*320 + slot];
                const short8 v1 = *(const short8*)&vt[(16+li)*320 + slot];
                o0 = MFMA16(v0, pu.s8, o0);
                o1 = MFMA16(v1, pu.s8, o1);
            }
            __builtin_amdgcn_s_setprio(0);
        }

        rsum += __shfl_xor(rsum, 16);
        rsum += __shfl_xor(rsum, 32);
        const float inv = frcp(rsum);

        u16* dst = Aout + qpos_out*DD + h*DHH;
        #pragma unroll
        for (int et = 0; et < 2; ++et){
            const f32x4 oo = et ? o1 : o0;
            uint2 o;
            o.x = cvtpk(oo[0]*inv, oo[1]*inv);
            o.y = cvtpk(oo[2]*inv, oo[3]*inv);
            *(uint2*)(dst + et*16 + g*4) = o;
        }
    }
}

// ---------------- host-side launch ----------------
extern "C" void kernel_launch(void* const* d_in, const int* in_sizes, int n_in,
                              void* d_out, int out_size, void* d_ws, size_t ws_size,
                              hipStream_t stream)
{
    const float* x = (const float*)d_in[0];
    float* out = (float*)d_out;
    char* ws = (char*)d_ws;

    u16*   Aatt  = (u16*)ws;                                  // [pos][128] bf16
    float* biasT = (float*)(ws + (size_t)NP*DD*2);            // NH*NP f32, attn-tiled
    u16*   Pq    = (u16*)(ws + (size_t)NP*DD*2 + (size_t)NH*NP*4);  // [h][pos][32]
    u16*   Pk    = Pq + (size_t)NP*DD;
    u16*   Pv    = Pk + (size_t)NP*DD;
    u16*   Pg    = Pv + (size_t)NP*DD;                        // [pos][128]
    u16*   Wpck  = Pg + (size_t)NP*DD;                        // 10*2048*8 bf16 (swizzled)

    {
        const float* w0 = (const float*)d_in[4];               // o_wq
        const float* w1 = (const float*)d_in[5];               // o_wkv (K rows)
        const float* w2 = (const float*)d_in[5] + DD*DD;       // o_wkv (V rows)
        const float* w3 = (const float*)d_in[6];               // o_wg
        const float* w4 = (const float*)d_in[8];               // o_wo
        const float* w5 = (const float*)d_in[13];              // i_wq
        const float* w6 = (const float*)d_in[14];              // i_wkv (K rows)
        const float* w7 = (const float*)d_in[14] + DD*DD;      // i_wkv (V rows)
        const float* w8 = (const float*)d_in[15];              // i_wg
        const float* w9 = (const float*)d_in[17];              // i_wo
        k_pack<<<80, 256, 0, stream>>>(w0,w1,w2,w3,w4,w5,w6,w7,w8,w9, Wpck);
    }

    for (int pass = 0; pass < 2; ++pass){
        void* const* W = d_in + 1 + pass*9;
        const float* ng = (const float*)W[0];
        const float* nb = (const float*)W[1];
        const float* wb = (const float*)W[2];
        const float* bg = (const float*)W[6];
        const float* bo = (const float*)W[8];
        const float* xin = (pass == 0) ? x : out;
        const u16* Wp = Wpck + (size_t)pass*5*2048*8;

        if (pass == 0){
            k_lnqkvg<0><<<NP/64, 256, 0, stream>>>(xin, ng, nb, wb, Wp, bg, biasT, Pq, Pk, Pv, Pg);
            k_attn_mfma<1><<<dim3(NH, NN), 256, 0, stream>>>(Pq, Pk, Pv, biasT, Aatt);
        } else {
            k_lnqkvg<1><<<NP/64, 256, 0, stream>>>(xin, ng, nb, wb, Wp, bg, biasT, Pq, Pk, Pv, Pg);
            k_attn_mfma<0><<<dim3(NH, NN), 256, 0, stream>>>(Pq, Pk, Pv, biasT, Aatt);
        }
        k_oproj<<<NP/128, 256, 0, stream>>>(Aatt, Pg, Wp, out, bo, xin);
    }
}